// Round 6
// baseline (403.710 us; speedup 1.0000x reference)
//
#include <hip/hip_runtime.h>
#include <math.h>

#define T_STEPS 32
#define NB 64      // batch
#define CC 512     // channels
#define AA 32      // cc_acc size
#define MROWS (T_STEPS * NB)   // 2048 GEMM rows

typedef __attribute__((ext_vector_type(8))) short bf16x8;
typedef __attribute__((ext_vector_type(4))) float f32x4;

__device__ __forceinline__ float sig_decay(const float* wp) {
    // decay = 1 - sigmoid(w)
    return 1.0f - 1.0f / (1.0f + expf(-wp[0]));
}

__device__ __forceinline__ unsigned short f2bf_rne(float f) {
    unsigned int u = __float_as_uint(f);
    u += 0x7FFF + ((u >> 16) & 1);      // round-to-nearest-even
    return (unsigned short)(u >> 16);
}

// ---------------------------------------------------------------------------
// Split fp32 weights into 3 bf16 planes (hi, mid, lo).  w ~= h + m + l with
// residual ~2^-27|w|.  Binary spikes make each MFMA product exact, so the
// 3-plane MFMA GEMM reproduces fp32 accuracy.
// ---------------------------------------------------------------------------
__global__ __launch_bounds__(256) void split_w_kernel(
    const float* __restrict__ W, unsigned short* __restrict__ out, int n)
{
    int i = blockIdx.x * 256 + threadIdx.x;
    if (i >= n) return;
    float w = W[i];
    unsigned short h = f2bf_rne(w);
    float fh = __uint_as_float((unsigned int)h << 16);
    float r = w - fh;
    unsigned short m = f2bf_rne(r);
    float fm = __uint_as_float((unsigned int)m << 16);
    unsigned short l = f2bf_rne(r - fm);
    out[i] = h; out[n + i] = m; out[2 * n + i] = l;
}

// ---------------------------------------------------------------------------
// Front end: transpose + synapse(tau=2) + jeffress(2->32) + LIF(1.5) +
// synapse(sf0) + w_cc(32->1) + IF.  One thread per (n,c), loops t.
// spike_out != null: raw IF spikes as bf16 (MFMA path; sf1 commutes past
// GEMM1).  Else legacy: apply sf1 filter, write fp32.
// ---------------------------------------------------------------------------
__global__ __launch_bounds__(256) void front_kernel(
    const float* __restrict__ x, const float* __restrict__ w_jeff,
    const float* __restrict__ w_cc, const float* __restrict__ w_sf0,
    const float* __restrict__ w_sf1,
    unsigned short* __restrict__ spike_out, float* __restrict__ filt_out)
{
    __shared__ float wj[2 * AA];
    __shared__ float wcc[AA];
    int tid = threadIdx.x;
    if (tid < 2 * AA) wj[tid] = w_jeff[tid];
    if (tid < AA) wcc[tid] = w_cc[tid];
    __syncthreads();

    int g = blockIdx.x * 256 + tid;     // n*CC + c
    int n = g >> 9;
    int c = g & (CC - 1);

    const float inv_lif = 1.0f / 1.5f;
    float d0 = sig_decay(w_sf0);
    float d1 = sig_decay(w_sf1);

    float s0 = 0.f, s1 = 0.f, v6 = 0.f, u1 = 0.f;
    float v[AA], u[AA];
#pragma unroll
    for (int a = 0; a < AA; a++) { v[a] = 0.f; u[a] = 0.f; }

    for (int t = 0; t < T_STEPS; t++) {
        const float* xp = x + (size_t)((t * NB + n) * 2) * CC + c;
        s0 = s0 * 0.5f + xp[0];
        s1 = s1 * 0.5f + xp[CC];
        float acc = 0.f;
#pragma unroll
        for (int a = 0; a < AA; a++) {
            float z  = wj[2 * a] * s0 + wj[2 * a + 1] * s1;
            float vv = v[a] + (z - v[a]) * inv_lif;
            bool  sp = vv >= 1.0f;
            v[a] = sp ? 0.0f : vv;
            float uu = u[a] * d0 + (sp ? 1.0f : 0.0f);
            u[a] = uu;
            acc += wcc[a] * uu;
        }
        v6 += acc;                                    // IFNode
        bool sp6 = v6 >= 1.0f;
        v6 = sp6 ? 0.0f : v6;
        size_t idx = (size_t)(t * NB + n) * CC + c;
        if (spike_out) {
            spike_out[idx] = sp6 ? (unsigned short)0x3F80 : (unsigned short)0;
        } else {
            u1 = u1 * d1 + (sp6 ? 1.0f : 0.0f);
            filt_out[idx] = u1;
        }
    }
}

// ---------------------------------------------------------------------------
// MFMA-path consumer: sum split-K parts of G = W·s (fixed order ->
// deterministic), apply commuted input filter zf = zf*d + G[t], IF, emit
// spikes (bf16 for next GEMM or fp32 for the final dot).
// ---------------------------------------------------------------------------
__global__ __launch_bounds__(256) void if_spike_kernel(
    const float* __restrict__ G, size_t partStride, int nparts,
    const float* __restrict__ w_sf_in, int F,
    unsigned short* __restrict__ out_bf, float* __restrict__ out_f32)
{
    int tid = blockIdx.x * 256 + threadIdx.x;   // n*F + f
    const int NF = NB * F;
    float dz = sig_decay(w_sf_in);
    float zf = 0.f, v = 0.f;
    for (int t = 0; t < T_STEPS; t++) {
        size_t off = (size_t)t * NF + tid;
        float gsum = G[off];
        for (int p = 1; p < nparts; p++) gsum += G[p * partStride + off];
        zf = zf * dz + gsum;      // commuted synapse filter
        v += zf;                  // IF
        bool sp = v >= 1.0f;
        v = sp ? 0.0f : v;
        if (out_bf) out_bf[off] = sp ? (unsigned short)0x3F80 : (unsigned short)0;
        else        out_f32[off] = sp ? 1.0f : 0.0f;
    }
}

// ---------------------------------------------------------------------------
// Binary-A bf16 MFMA GEMM:  C(part z) = A(spikes, MxK bf16) @ B^T where B is
// 3 bf16 planes (N,K) summed into one fp32 accumulator (exact for binary A).
// 128x128 tile, BK=32, 256 threads = 4 waves; wave = 128m x 32n strip.
//
// Grid is 1-D (GX * 16 * SK blocks) with an XCD-aware decode: workgroup ->
// XCD is bid%8 (round-robin), so we place all 16 m-blocks of one
// (n-tile, k-slice) column on ONE XCD: its B slice is fetched once into that
// XCD's 4 MB L2 and reused 16x.  Requires GX*SK ∈ {16, 32}.
// ---------------------------------------------------------------------------
__global__ __launch_bounds__(256) void bgemm(
    const unsigned short* __restrict__ A,   // M x K spikes (bf16)
    const unsigned short* __restrict__ B,   // 3 planes of N x K (bf16)
    float* __restrict__ C,                  // SK x M x N fp32 partials
    int N, int K_total, int K_per, int GX)
{
    __shared__ __align__(16) unsigned int As[128 * 20];       // 10 KB
    __shared__ __align__(16) unsigned int Bs[3 * 128 * 20];   // 30 KB

    const int tid = threadIdx.x;
    const int w   = tid >> 6;         // wave 0..3
    const int L   = tid & 63;

    // XCD-aware decode: bid%8 = XCD; same column (x,z) -> same XCD.
    const int bid  = blockIdx.x;
    const int xcd  = bid & 7;
    const int slot = bid >> 3;
    const int col  = (slot >> 4) * 8 + xcd;   // 0 .. GX*SK-1
    const int y    = slot & 15;               // m-tile
    const int x    = col % GX;                // n-tile
    const int z    = col / GX;                // k-slice

    const int bm  = y * 128;
    const int bn  = x * 128;
    const int kbeg = z * K_per;

    f32x4 acc[8][2];
#pragma unroll
    for (int i = 0; i < 8; i++)
#pragma unroll
        for (int j = 0; j < 2; j++) acc[i][j] = (f32x4){0.f, 0.f, 0.f, 0.f};

    // staging: A 128x32bf16 = 512 chunks(16B), 2/thread; B 3x128x32 = 6/thread
    uint4 pa[2], pb[6];
    auto gload = [&](int k0) {
#pragma unroll
        for (int i = 0; i < 2; i++) {
            int idx = tid + i * 256;
            int r = idx >> 2, c = idx & 3;
            pa[i] = *(const uint4*)(A + (size_t)(bm + r) * K_total + k0 + c * 8);
        }
#pragma unroll
        for (int i = 0; i < 6; i++) {
            int idx = tid + i * 256;
            int p = idx >> 9, rem = idx & 511;
            int r = rem >> 2, c = rem & 3;
            pb[i] = *(const uint4*)(B + ((size_t)p * N + bn + r) * K_total + k0 + c * 8);
        }
    };
    auto lwrite = [&]() {
#pragma unroll
        for (int i = 0; i < 2; i++) {
            int idx = tid + i * 256;
            int r = idx >> 2, c = idx & 3;
            *(uint4*)&As[r * 20 + c * 4] = pa[i];
        }
#pragma unroll
        for (int i = 0; i < 6; i++) {
            int idx = tid + i * 256;
            int p = idx >> 9, rem = idx & 511;
            int r = rem >> 2, c = rem & 3;
            *(uint4*)&Bs[p * 2560 + r * 20 + c * 4] = pb[i];
        }
    };

    const int lrow = L & 15;
    const int lq   = L >> 4;

    gload(kbeg);
    const int nk = K_per / 32;
    for (int kt = 0; kt < nk; kt++) {
        lwrite();
        __syncthreads();
        if (kt + 1 < nk) gload(kbeg + (kt + 1) * 32);   // prefetch to regs

        bf16x8 a[8];
#pragma unroll
        for (int i = 0; i < 8; i++)
            a[i] = *(const bf16x8*)&As[(i * 16 + lrow) * 20 + lq * 4];
#pragma unroll
        for (int p = 0; p < 3; p++) {
#pragma unroll
            for (int j = 0; j < 2; j++) {
                bf16x8 b = *(const bf16x8*)
                    &Bs[p * 2560 + (w * 32 + j * 16 + lrow) * 20 + lq * 4];
#pragma unroll
                for (int i = 0; i < 8; i++)
                    acc[i][j] = __builtin_amdgcn_mfma_f32_16x16x32_bf16(
                        a[i], b, acc[i][j], 0, 0, 0);
            }
        }
        __syncthreads();
    }

    // C/D layout (m89-verified): col = lane&15, row = (lane>>4)*4 + reg
    float* Cp = C + (size_t)z * (size_t)MROWS * N;
#pragma unroll
    for (int i = 0; i < 8; i++) {
#pragma unroll
        for (int j = 0; j < 2; j++) {
            int cc = bn + w * 32 + j * 16 + lrow;
            size_t base = (size_t)(bm + i * 16 + lq * 4) * N + cc;
#pragma unroll
            for (int r = 0; r < 4; r++)
                Cp[base + (size_t)r * N] = acc[i][j][r];
        }
    }
}

// ---------------------------------------------------------------------------
// Legacy fp32 path (round-3, proven): used only if ws_size is too small.
// ---------------------------------------------------------------------------
__global__ __launch_bounds__(256) void if_filter_kernel(
    float* __restrict__ buf, size_t partStride, int nparts,
    const float* __restrict__ w_sf, int F)
{
    int tid = blockIdx.x * 256 + threadIdx.x;
    const int NF = NB * F;
    bool  filt = (w_sf != nullptr);
    float d = filt ? sig_decay(w_sf) : 0.0f;
    float v = 0.f, u = 0.f;
    for (int t = 0; t < T_STEPS; t++) {
        size_t off = (size_t)t * NF + tid;
        float zt = buf[off];
        for (int p = 1; p < nparts; p++) zt += buf[p * partStride + off];
        v += zt;
        bool sp = v >= 1.0f;
        v = sp ? 0.0f : v;
        float s = sp ? 1.0f : 0.0f;
        if (filt) { u = u * d + s; buf[off] = u; }
        else      { buf[off] = s; }
    }
}

__global__ __launch_bounds__(256) void gemm_nt(
    const float* __restrict__ A, const float* __restrict__ B,
    float* __restrict__ C, int M, int N, int K_total, int K_per)
{
    constexpr int BM = 64, BN = 64, BK = 32;
    __shared__ float As[BK][BM + 4];
    __shared__ float Bs[BK][BN + 4];
    const int tid = threadIdx.x;
    const int tx  = tid & 15;
    const int ty  = tid >> 4;
    const int bm  = blockIdx.y * BM;
    const int bn  = blockIdx.x * BN;
    const int kbeg = blockIdx.z * K_per;
    float acc[4][4];
#pragma unroll
    for (int i = 0; i < 4; i++)
#pragma unroll
        for (int j = 0; j < 4; j++) acc[i][j] = 0.f;
    const int lrow = tid >> 3;
    const int lkq  = tid & 7;
    for (int kt = 0; kt < K_per; kt += BK) {
        int k0 = kbeg + kt;
        __syncthreads();
#pragma unroll
        for (int i = 0; i < 2; i++) {
            int row = lrow + i * 32;
            float4 av = *(const float4*)(A + (size_t)(bm + row) * K_total + k0 + lkq * 4);
            As[lkq * 4 + 0][row] = av.x;
            As[lkq * 4 + 1][row] = av.y;
            As[lkq * 4 + 2][row] = av.z;
            As[lkq * 4 + 3][row] = av.w;
            float4 bv = *(const float4*)(B + (size_t)(bn + row) * K_total + k0 + lkq * 4);
            Bs[lkq * 4 + 0][row] = bv.x;
            Bs[lkq * 4 + 1][row] = bv.y;
            Bs[lkq * 4 + 2][row] = bv.z;
            Bs[lkq * 4 + 3][row] = bv.w;
        }
        __syncthreads();
#pragma unroll
        for (int kk = 0; kk < BK; kk++) {
            float4 a0 = *(const float4*)&As[kk][ty * 4];
            float4 b0 = *(const float4*)&Bs[kk][tx * 4];
            float ar[4] = {a0.x, a0.y, a0.z, a0.w};
            float br[4] = {b0.x, b0.y, b0.z, b0.w};
#pragma unroll
            for (int i = 0; i < 4; i++)
#pragma unroll
                for (int j = 0; j < 4; j++) acc[i][j] += ar[i] * br[j];
        }
    }
    float* Cp = C + (size_t)blockIdx.z * (size_t)M * N;
#pragma unroll
    for (int i = 0; i < 4; i++) {
        float4 o;
        o.x = acc[i][0]; o.y = acc[i][1]; o.z = acc[i][2]; o.w = acc[i][3];
        *(float4*)(Cp + (size_t)(bm + ty * 4 + i) * N + bn + tx * 4) = o;
    }
}

// ---------------------------------------------------------------------------
// Final: out[t,n] = cumsum_t( dot(s3[t,n,:512], W_out) + b ).  One wave per n.
// ---------------------------------------------------------------------------
__global__ __launch_bounds__(64) void final_kernel(
    const float* __restrict__ y15, const float* __restrict__ W_out,
    const float* __restrict__ b_out, float* __restrict__ out)
{
    int n = blockIdx.x;
    int lane = threadIdx.x;
    float w[8];
#pragma unroll
    for (int j = 0; j < 8; j++) w[j] = W_out[lane + j * 64];
    float b = b_out[0];
    float cum = 0.f;
    for (int t = 0; t < T_STEPS; t++) {
        const float* yp = y15 + (size_t)(t * NB + n) * 512;
        float p = 0.f;
#pragma unroll
        for (int j = 0; j < 8; j++) p += yp[lane + j * 64] * w[j];
#pragma unroll
        for (int off = 32; off > 0; off >>= 1) p += __shfl_down(p, off);
        if (lane == 0) {
            cum += p + b;
            out[t * NB + n] = cum;
        }
    }
}

extern "C" void kernel_launch(void* const* d_in, const int* in_sizes, int n_in,
                              void* d_out, int out_size, void* d_ws, size_t ws_size,
                              hipStream_t stream) {
    (void)in_sizes; (void)n_in; (void)out_size;
    const float* x      = (const float*)d_in[0];
    const float* w_jeff = (const float*)d_in[1];
    const float* w_cc   = (const float*)d_in[2];
    const float* w_sf0  = (const float*)d_in[3];
    const float* W1     = (const float*)d_in[4];
    const float* w_sf1  = (const float*)d_in[5];
    const float* W2     = (const float*)d_in[6];
    const float* w_sf2  = (const float*)d_in[7];
    const float* W3     = (const float*)d_in[8];
    const float* w_sf3  = (const float*)d_in[9];
    const float* W_out  = (const float*)d_in[10];
    const float* b_out  = (const float*)d_in[11];
    float* out = (float*)d_out;
    const int M = MROWS;   // 2048

    const size_t nW1 = (size_t)2048 * 512, nW2 = (size_t)1024 * 2048, nW3 = (size_t)512 * 1024;
    const size_t planesB = 3 * (nW1 + nW2 + nW3) * 2;

    // workspace need for splitK config (sk1, sk2, sk3); G3 overlays G1 region.
    auto need_bytes = [&](int sk1, int sk2, int sk3) -> size_t {
        size_t g1 = (size_t)sk1 * M * 2048 * 4;
        size_t g3 = (size_t)sk3 * M * 512 * 4;
        size_t g1r = g1 > g3 ? g1 : g3;
        return planesB + (size_t)M * 512 * 2 + g1r + (size_t)sk2 * M * 1024 * 4
               + (size_t)M * 2048 * 2 + (size_t)M * 1024 * 2 + (size_t)M * 512 * 4;
    };

    int sk1, sk2, sk3;
    bool mfma_ok = true;
    if (ws_size >= need_bytes(2, 4, 8))       { sk1 = 2; sk2 = 4; sk3 = 8; }  // 512-block grids
    else if (ws_size >= need_bytes(1, 2, 4))  { sk1 = 1; sk2 = 2; sk3 = 4; }  // 256-block grids
    else                                      { sk1 = sk2 = sk3 = 0; mfma_ok = false; }

    if (mfma_ok) {
        // ---------------- MFMA (binary spikes x bf16-split-3) ----------------
        unsigned short* Ws1 = (unsigned short*)d_ws;
        unsigned short* Ws2 = Ws1 + 3 * nW1;
        unsigned short* Ws3 = Ws2 + 3 * nW2;
        unsigned short* s6  = Ws3 + 3 * nW3;
        size_t g1 = (size_t)sk1 * M * 2048, g3 = (size_t)sk3 * M * 512;
        size_t g1r = g1 > g3 ? g1 : g3;
        float* G1  = (float*)(s6 + (size_t)M * 512);
        float* G2  = G1 + g1r;
        unsigned short* s8  = (unsigned short*)(G2 + (size_t)sk2 * M * 1024);
        unsigned short* s10 = s8 + (size_t)M * 2048;
        float* s12 = (float*)(s10 + (size_t)M * 1024);
        float* G3  = G1;   // overlay: G1 dead once s8 exists

        split_w_kernel<<<(int)((nW1 + 255) / 256), 256, 0, stream>>>(W1, Ws1, (int)nW1);
        split_w_kernel<<<(int)((nW2 + 255) / 256), 256, 0, stream>>>(W2, Ws2, (int)nW2);
        split_w_kernel<<<(int)((nW3 + 255) / 256), 256, 0, stream>>>(W3, Ws3, (int)nW3);

        front_kernel<<<NB * CC / 256, 256, 0, stream>>>(
            x, w_jeff, w_cc, w_sf0, w_sf1, s6, nullptr);

        // GEMM1: G1 = s6 @ W1^T  (N=2048, K=512), GX=16, 16*16*sk1 blocks
        bgemm<<<16 * 16 * sk1, 256, 0, stream>>>(
            s6, Ws1, G1, 2048, 512, 512 / sk1, 16);
        if_spike_kernel<<<NB * 2048 / 256, 256, 0, stream>>>(
            G1, (size_t)M * 2048, sk1, w_sf1, 2048, s8, nullptr);

        // GEMM2: G2 = s8 @ W2^T  (N=1024, K=2048), GX=8
        bgemm<<<8 * 16 * sk2, 256, 0, stream>>>(
            s8, Ws2, G2, 1024, 2048, 2048 / sk2, 8);
        if_spike_kernel<<<NB * 1024 / 256, 256, 0, stream>>>(
            G2, (size_t)M * 1024, sk2, w_sf2, 1024, s10, nullptr);

        // GEMM3: G3 = s10 @ W3^T (N=512, K=1024), GX=4
        bgemm<<<4 * 16 * sk3, 256, 0, stream>>>(
            s10, Ws3, G3, 512, 1024, 1024 / sk3, 4);
        if_spike_kernel<<<NB * 512 / 256, 256, 0, stream>>>(
            G3, (size_t)M * 512, sk3, w_sf3, 512, nullptr, s12);

        final_kernel<<<NB, 64, 0, stream>>>(s12, W_out, b_out, out);
    } else {
        // ---------------- legacy fp32 path (round-3) ----------------
        float* y7  = (float*)d_ws;
        float* z1  = y7 + (size_t)M * 512;
        float* z2p = z1 + (size_t)M * 2048;
        float* z3p = z1;
        size_t need2 = ((size_t)M * 512 + (size_t)M * 2048 + 2 * (size_t)M * 1024) * 4;
        const int ksplit2 = (ws_size >= need2) ? 2 : 1;

        front_kernel<<<NB * CC / 256, 256, 0, stream>>>(
            x, w_jeff, w_cc, w_sf0, w_sf1, nullptr, y7);
        gemm_nt<<<dim3(2048 / 64, 2048 / 64, 1), 256, 0, stream>>>(
            y7, W1, z1, M, 2048, 512, 512);
        if_filter_kernel<<<NB * 2048 / 256, 256, 0, stream>>>(z1, 0, 1, w_sf2, 2048);
        gemm_nt<<<dim3(1024 / 64, 2048 / 64, ksplit2), 256, 0, stream>>>(
            z1, W2, z2p, M, 1024, 2048, 2048 / ksplit2);
        if_filter_kernel<<<NB * 1024 / 256, 256, 0, stream>>>(
            z2p, (size_t)M * 1024, ksplit2, w_sf3, 1024);
        gemm_nt<<<dim3(512 / 64, 2048 / 64, 4), 256, 0, stream>>>(
            z2p, W3, z3p, M, 512, 1024, 1024 / 4);
        if_filter_kernel<<<NB * 512 / 256, 256, 0, stream>>>(
            z3p, (size_t)M * 512, 4, nullptr, 512);
        final_kernel<<<NB, 64, 0, stream>>>(z3p, W_out, b_out, out);
    }
}

// Round 7
// 329.444 us; speedup vs baseline: 1.2254x; 1.2254x over previous
//
#include <hip/hip_runtime.h>
#include <math.h>

#define T_STEPS 32
#define NB 64      // batch
#define CC 512     // channels
#define AA 32      // cc_acc size
#define MROWS (T_STEPS * NB)   // 2048 GEMM rows

typedef __attribute__((ext_vector_type(8)))  short bf16x8;
typedef __attribute__((ext_vector_type(16))) float f32x16;

__device__ __forceinline__ float sig_decay(const float* wp) {
    return 1.0f - 1.0f / (1.0f + expf(-wp[0]));   // 1 - sigmoid(w)
}

__device__ __forceinline__ unsigned short f2bf_rne(float f) {
    unsigned int u = __float_as_uint(f);
    u += 0x7FFF + ((u >> 16) & 1);
    return (unsigned short)(u >> 16);
}

// ---------------------------------------------------------------------------
// Split fp32 weights into 3 bf16 planes (hi, mid, lo); residual ~2^-27|w|.
// Binary spike A makes each MFMA product exact -> fp32-accuracy GEMM.
// ---------------------------------------------------------------------------
__global__ __launch_bounds__(256) void split_w_kernel(
    const float* __restrict__ W, unsigned short* __restrict__ out, int n)
{
    int i = blockIdx.x * 256 + threadIdx.x;
    if (i >= n) return;
    float w = W[i];
    unsigned short h = f2bf_rne(w);
    float fh = __uint_as_float((unsigned int)h << 16);
    float r = w - fh;
    unsigned short m = f2bf_rne(r);
    float fm = __uint_as_float((unsigned int)m << 16);
    unsigned short l = f2bf_rne(r - fm);
    out[i] = h; out[n + i] = m; out[2 * n + i] = l;
}

// ---------------------------------------------------------------------------
// Front end (transpose + synapse tau=2 + jeffress + LIF + sf0 + w_cc + IF).
// spike_out != null: raw IF spikes as bf16.  Else legacy fp32 with sf1.
// ---------------------------------------------------------------------------
__global__ __launch_bounds__(256) void front_kernel(
    const float* __restrict__ x, const float* __restrict__ w_jeff,
    const float* __restrict__ w_cc, const float* __restrict__ w_sf0,
    const float* __restrict__ w_sf1,
    unsigned short* __restrict__ spike_out, float* __restrict__ filt_out)
{
    __shared__ float wj[2 * AA];
    __shared__ float wcc[AA];
    int tid = threadIdx.x;
    if (tid < 2 * AA) wj[tid] = w_jeff[tid];
    if (tid < AA) wcc[tid] = w_cc[tid];
    __syncthreads();

    int g = blockIdx.x * 256 + tid;     // n*CC + c
    int n = g >> 9;
    int c = g & (CC - 1);

    const float inv_lif = 1.0f / 1.5f;
    float d0 = sig_decay(w_sf0);
    float d1 = sig_decay(w_sf1);

    float s0 = 0.f, s1 = 0.f, v6 = 0.f, u1 = 0.f;
    float v[AA], u[AA];
#pragma unroll
    for (int a = 0; a < AA; a++) { v[a] = 0.f; u[a] = 0.f; }

    for (int t = 0; t < T_STEPS; t++) {
        const float* xp = x + (size_t)((t * NB + n) * 2) * CC + c;
        s0 = s0 * 0.5f + xp[0];
        s1 = s1 * 0.5f + xp[CC];
        float acc = 0.f;
#pragma unroll
        for (int a = 0; a < AA; a++) {
            float z  = wj[2 * a] * s0 + wj[2 * a + 1] * s1;
            float vv = v[a] + (z - v[a]) * inv_lif;
            bool  sp = vv >= 1.0f;
            v[a] = sp ? 0.0f : vv;
            float uu = u[a] * d0 + (sp ? 1.0f : 0.0f);
            u[a] = uu;
            acc += wcc[a] * uu;
        }
        v6 += acc;
        bool sp6 = v6 >= 1.0f;
        v6 = sp6 ? 0.0f : v6;
        size_t idx = (size_t)(t * NB + n) * CC + c;
        if (spike_out) {
            spike_out[idx] = sp6 ? (unsigned short)0x3F80 : (unsigned short)0;
        } else {
            u1 = u1 * d1 + (sp6 ? 1.0f : 0.0f);
            filt_out[idx] = u1;
        }
    }
}

// ---------------------------------------------------------------------------
// Sum split-K parts of G (fixed order), commuted filter, IF, emit spikes.
// ---------------------------------------------------------------------------
__global__ __launch_bounds__(256) void if_spike_kernel(
    const float* __restrict__ G, size_t partStride, int nparts,
    const float* __restrict__ w_sf_in, int F,
    unsigned short* __restrict__ out_bf, float* __restrict__ out_f32)
{
    int tid = blockIdx.x * 256 + threadIdx.x;   // n*F + f
    const int NF = NB * F;
    float dz = sig_decay(w_sf_in);
    float zf = 0.f, v = 0.f;
    for (int t = 0; t < T_STEPS; t++) {
        size_t off = (size_t)t * NF + tid;
        float gsum = G[off];
        for (int p = 1; p < nparts; p++) gsum += G[p * partStride + off];
        zf = zf * dz + gsum;
        v += zf;
        bool sp = v >= 1.0f;
        v = sp ? 0.0f : v;
        if (out_bf) out_bf[off] = sp ? (unsigned short)0x3F80 : (unsigned short)0;
        else        out_f32[off] = sp ? 1.0f : 0.0f;
    }
}

// ---------------------------------------------------------------------------
// Binary-A bf16 MFMA GEMM, 32x32x16, 3 weight planes into shared fp32 acc.
// Block: 512 threads = 8 waves = 4 spatial (64m x 64n) x 2 k-groups.
// Block tile 128m x 128n, BK=32 (16 k per k-group per stage).
// LDS holds the stage in MFMA fragment order (16-B chunks, lanes consecutive
// -> conflict-free ds_read_b128).  K-group accs combined via LDS; only
// k-group 0 writes C, so global partials = blockIdx.z only.
// ---------------------------------------------------------------------------
__global__ __launch_bounds__(512, 2) void bgemm(
    const unsigned short* __restrict__ A,   // M x K spikes (bf16)
    const unsigned short* __restrict__ B,   // 3 planes of N x K (bf16)
    float* __restrict__ C,                  // sk x M x N fp32 partials
    int N, int K_total, int K_per)
{
    // 2048 16-B chunks: A = 512 (128 rows x 4), B = 1536 (3 x 128 x 4)
    __shared__ __align__(16) unsigned int sh[2048 * 4];   // 32 KB

    const int tid = threadIdx.x;
    const int wv  = tid >> 6;         // 0..7
    const int L   = tid & 63;
    const int sn  = wv & 1;           // n-half (64)
    const int sm  = (wv >> 1) & 1;    // m-half (64)
    const int g   = wv >> 2;          // k-group (16-k half of each stage)

    const int bm  = blockIdx.y * 128;
    const int bn  = blockIdx.x * 128;
    const int kbeg = blockIdx.z * K_per;

    f32x16 acc[2][2];
#pragma unroll
    for (int i = 0; i < 2; i++)
#pragma unroll
        for (int j = 0; j < 2; j++)
#pragma unroll
            for (int r = 0; r < 16; r++) acc[i][j][r] = 0.f;

    // ---- staging: one A chunk + three B chunks per thread ----
    uint4 pa, pb[3];
    auto gload = [&](int k0) {
        {
            int c = tid & 3, r = tid >> 2;                 // A chunk
            pa = *(const uint4*)(A + (size_t)(bm + r) * K_total + k0 + c * 8);
        }
#pragma unroll
        for (int i = 0; i < 3; i++) {
            int id = i * 512 + tid;                        // B chunk
            int c = id & 3, n = (id >> 2) & 127, p = id >> 9;
            pb[i] = *(const uint4*)(B + ((size_t)p * N + bn + n) * K_total + k0 + c * 8);
        }
    };
    auto lwrite = [&]() {
        {
            int c = tid & 3, r = tid >> 2;
            int off = ((c >> 1) * 4 + (r >> 5)) * 64 + (r & 31) + 32 * (c & 1);
            *(uint4*)&sh[off * 4] = pa;
        }
#pragma unroll
        for (int i = 0; i < 3; i++) {
            int id = i * 512 + tid;
            int c = id & 3, n = (id >> 2) & 127, p = id >> 9;
            int off = 512 + (((c >> 1) * 3 + p) * 4 + (n >> 5)) * 64 + (n & 31) + 32 * (c & 1);
            *(uint4*)&sh[off * 4] = pb[i];
        }
    };

    gload(kbeg);
    const int nk = K_per / 32;
    for (int kt = 0; kt < nk; kt++) {
        lwrite();
        __syncthreads();
        if (kt + 1 < nk) gload(kbeg + (kt + 1) * 32);

        bf16x8 a0 = *(const bf16x8*)&sh[((g * 4 + sm * 2 + 0) * 64 + L) * 4];
        bf16x8 a1 = *(const bf16x8*)&sh[((g * 4 + sm * 2 + 1) * 64 + L) * 4];
#pragma unroll
        for (int p = 0; p < 3; p++) {
#pragma unroll
            for (int j = 0; j < 2; j++) {
                bf16x8 b = *(const bf16x8*)
                    &sh[(512 + ((g * 3 + p) * 4 + sn * 2 + j) * 64 + L) * 4];
                acc[0][j] = __builtin_amdgcn_mfma_f32_32x32x16_bf16(a0, b, acc[0][j], 0, 0, 0);
                acc[1][j] = __builtin_amdgcn_mfma_f32_32x32x16_bf16(a1, b, acc[1][j], 0, 0, 0);
            }
        }
        __syncthreads();
    }

    // ---- combine k-groups through LDS (g0 + g1, fixed order) ----
    // C/D layout (m74/m101): col = lane&31, row = (reg&3)+8*(reg>>2)+4*(lane>>5)
    float* shf = (float*)sh;     // 8192 floats = 32 KB, stage is dead
    const int col = L & 31;
    const int rhi = 4 * (L >> 5);
#pragma unroll
    for (int rm = 0; rm < 2; rm++) {
        if (g == 1 && sm == rm) {
#pragma unroll
            for (int i = 0; i < 2; i++)
#pragma unroll
                for (int j = 0; j < 2; j++)
#pragma unroll
                    for (int r = 0; r < 16; r++) {
                        int row = (r & 3) + 8 * (r >> 2) + rhi;
                        shf[sn * 4096 + (i * 32 + row) * 64 + j * 32 + col] = acc[i][j][r];
                    }
        }
        __syncthreads();
        if (g == 0 && sm == rm) {
#pragma unroll
            for (int i = 0; i < 2; i++)
#pragma unroll
                for (int j = 0; j < 2; j++)
#pragma unroll
                    for (int r = 0; r < 16; r++) {
                        int row = (r & 3) + 8 * (r >> 2) + rhi;
                        acc[i][j][r] += shf[sn * 4096 + (i * 32 + row) * 64 + j * 32 + col];
                    }
        }
        __syncthreads();
    }

    if (g == 0) {
        float* Cp = C + (size_t)blockIdx.z * (size_t)MROWS * N;
#pragma unroll
        for (int i = 0; i < 2; i++)
#pragma unroll
            for (int j = 0; j < 2; j++) {
                int cc = bn + sn * 64 + j * 32 + col;
#pragma unroll
                for (int r = 0; r < 16; r++) {
                    int row = bm + sm * 64 + i * 32 + (r & 3) + 8 * (r >> 2) + rhi;
                    Cp[(size_t)row * N + cc] = acc[i][j][r];
                }
            }
    }
}

// ---------------------------------------------------------------------------
// Legacy fp32 path (round-3, proven) for small workspace.
// ---------------------------------------------------------------------------
__global__ __launch_bounds__(256) void if_filter_kernel(
    float* __restrict__ buf, size_t partStride, int nparts,
    const float* __restrict__ w_sf, int F)
{
    int tid = blockIdx.x * 256 + threadIdx.x;
    const int NF = NB * F;
    bool  filt = (w_sf != nullptr);
    float d = filt ? sig_decay(w_sf) : 0.0f;
    float v = 0.f, u = 0.f;
    for (int t = 0; t < T_STEPS; t++) {
        size_t off = (size_t)t * NF + tid;
        float zt = buf[off];
        for (int p = 1; p < nparts; p++) zt += buf[p * partStride + off];
        v += zt;
        bool sp = v >= 1.0f;
        v = sp ? 0.0f : v;
        float s = sp ? 1.0f : 0.0f;
        if (filt) { u = u * d + s; buf[off] = u; }
        else      { buf[off] = s; }
    }
}

__global__ __launch_bounds__(256) void gemm_nt(
    const float* __restrict__ A, const float* __restrict__ B,
    float* __restrict__ C, int M, int N, int K_total, int K_per)
{
    constexpr int BM = 64, BN = 64, BK = 32;
    __shared__ float As[BK][BM + 4];
    __shared__ float Bs[BK][BN + 4];
    const int tid = threadIdx.x;
    const int tx  = tid & 15;
    const int ty  = tid >> 4;
    const int bm  = blockIdx.y * BM;
    const int bn  = blockIdx.x * BN;
    const int kbeg = blockIdx.z * K_per;
    float acc[4][4];
#pragma unroll
    for (int i = 0; i < 4; i++)
#pragma unroll
        for (int j = 0; j < 4; j++) acc[i][j] = 0.f;
    const int lrow = tid >> 3;
    const int lkq  = tid & 7;
    for (int kt = 0; kt < K_per; kt += BK) {
        int k0 = kbeg + kt;
        __syncthreads();
#pragma unroll
        for (int i = 0; i < 2; i++) {
            int row = lrow + i * 32;
            float4 av = *(const float4*)(A + (size_t)(bm + row) * K_total + k0 + lkq * 4);
            As[lkq * 4 + 0][row] = av.x;
            As[lkq * 4 + 1][row] = av.y;
            As[lkq * 4 + 2][row] = av.z;
            As[lkq * 4 + 3][row] = av.w;
            float4 bv = *(const float4*)(B + (size_t)(bn + row) * K_total + k0 + lkq * 4);
            Bs[lkq * 4 + 0][row] = bv.x;
            Bs[lkq * 4 + 1][row] = bv.y;
            Bs[lkq * 4 + 2][row] = bv.z;
            Bs[lkq * 4 + 3][row] = bv.w;
        }
        __syncthreads();
#pragma unroll
        for (int kk = 0; kk < BK; kk++) {
            float4 a0 = *(const float4*)&As[kk][ty * 4];
            float4 b0 = *(const float4*)&Bs[kk][tx * 4];
            float ar[4] = {a0.x, a0.y, a0.z, a0.w};
            float br[4] = {b0.x, b0.y, b0.z, b0.w};
#pragma unroll
            for (int i = 0; i < 4; i++)
#pragma unroll
                for (int j = 0; j < 4; j++) acc[i][j] += ar[i] * br[j];
        }
    }
    float* Cp = C + (size_t)blockIdx.z * (size_t)M * N;
#pragma unroll
    for (int i = 0; i < 4; i++) {
        float4 o;
        o.x = acc[i][0]; o.y = acc[i][1]; o.z = acc[i][2]; o.w = acc[i][3];
        *(float4*)(Cp + (size_t)(bm + ty * 4 + i) * N + bn + tx * 4) = o;
    }
}

// ---------------------------------------------------------------------------
// Final: out[t,n] = cumsum_t( dot(s3[t,n,:512], W_out) + b ).  One wave per n.
// ---------------------------------------------------------------------------
__global__ __launch_bounds__(64) void final_kernel(
    const float* __restrict__ y15, const float* __restrict__ W_out,
    const float* __restrict__ b_out, float* __restrict__ out)
{
    int n = blockIdx.x;
    int lane = threadIdx.x;
    float w[8];
#pragma unroll
    for (int j = 0; j < 8; j++) w[j] = W_out[lane + j * 64];
    float b = b_out[0];
    float cum = 0.f;
    for (int t = 0; t < T_STEPS; t++) {
        const float* yp = y15 + (size_t)(t * NB + n) * 512;
        float p = 0.f;
#pragma unroll
        for (int j = 0; j < 8; j++) p += yp[lane + j * 64] * w[j];
#pragma unroll
        for (int off = 32; off > 0; off >>= 1) p += __shfl_down(p, off);
        if (lane == 0) {
            cum += p + b;
            out[t * NB + n] = cum;
        }
    }
}

extern "C" void kernel_launch(void* const* d_in, const int* in_sizes, int n_in,
                              void* d_out, int out_size, void* d_ws, size_t ws_size,
                              hipStream_t stream) {
    (void)in_sizes; (void)n_in; (void)out_size;
    const float* x      = (const float*)d_in[0];
    const float* w_jeff = (const float*)d_in[1];
    const float* w_cc   = (const float*)d_in[2];
    const float* w_sf0  = (const float*)d_in[3];
    const float* W1     = (const float*)d_in[4];
    const float* w_sf1  = (const float*)d_in[5];
    const float* W2     = (const float*)d_in[6];
    const float* w_sf2  = (const float*)d_in[7];
    const float* W3     = (const float*)d_in[8];
    const float* w_sf3  = (const float*)d_in[9];
    const float* W_out  = (const float*)d_in[10];
    const float* b_out  = (const float*)d_in[11];
    float* out = (float*)d_out;
    const int M = MROWS;   // 2048

    const size_t nW1 = (size_t)2048 * 512, nW2 = (size_t)1024 * 2048, nW3 = (size_t)512 * 1024;
    const size_t planesB = 3 * (nW1 + nW2 + nW3) * 2;
    const int sk1 = 1, sk2 = 2, sk3 = 4;

    size_t g1elts = (size_t)sk1 * M * 2048, g3elts = (size_t)sk3 * M * 512;
    size_t g1r = g1elts > g3elts ? g1elts : g3elts;
    size_t need = planesB + (size_t)M * 512 * 2 + g1r * 4
                + (size_t)sk2 * M * 1024 * 4
                + (size_t)M * 2048 * 2 + (size_t)M * 1024 * 2 + (size_t)M * 512 * 4;

    if (ws_size >= need) {
        // ---------------- MFMA (binary spikes x bf16-split-3) ----------------
        unsigned short* Ws1 = (unsigned short*)d_ws;
        unsigned short* Ws2 = Ws1 + 3 * nW1;
        unsigned short* Ws3 = Ws2 + 3 * nW2;
        unsigned short* s6  = Ws3 + 3 * nW3;
        float* G1  = (float*)(s6 + (size_t)M * 512);
        float* G2  = G1 + g1r;
        unsigned short* s8  = (unsigned short*)(G2 + (size_t)sk2 * M * 1024);
        unsigned short* s10 = s8 + (size_t)M * 2048;
        float* s12 = (float*)(s10 + (size_t)M * 1024);
        float* G3  = G1;   // overlay: G1 dead once s8 exists

        split_w_kernel<<<(int)((nW1 + 255) / 256), 256, 0, stream>>>(W1, Ws1, (int)nW1);
        split_w_kernel<<<(int)((nW2 + 255) / 256), 256, 0, stream>>>(W2, Ws2, (int)nW2);
        split_w_kernel<<<(int)((nW3 + 255) / 256), 256, 0, stream>>>(W3, Ws3, (int)nW3);

        front_kernel<<<NB * CC / 256, 256, 0, stream>>>(
            x, w_jeff, w_cc, w_sf0, w_sf1, s6, nullptr);

        // GEMM1: (2048x512) @ (2048x512)^T -> 2048x2048; 16x16x1 = 256 blocks
        bgemm<<<dim3(2048 / 128, 16, sk1), 512, 0, stream>>>(
            s6, Ws1, G1, 2048, 512, 512 / sk1);
        if_spike_kernel<<<NB * 2048 / 256, 256, 0, stream>>>(
            G1, (size_t)M * 2048, sk1, w_sf1, 2048, s8, nullptr);

        // GEMM2: K=2048, splitK=2; 8x16x2 = 256 blocks
        bgemm<<<dim3(1024 / 128, 16, sk2), 512, 0, stream>>>(
            s8, Ws2, G2, 1024, 2048, 2048 / sk2);
        if_spike_kernel<<<NB * 1024 / 256, 256, 0, stream>>>(
            G2, (size_t)M * 1024, sk2, w_sf2, 1024, s10, nullptr);

        // GEMM3: K=1024, splitK=4; 4x16x4 = 256 blocks
        bgemm<<<dim3(512 / 128, 16, sk3), 512, 0, stream>>>(
            s10, Ws3, G3, 512, 1024, 1024 / sk3);
        if_spike_kernel<<<NB * 512 / 256, 256, 0, stream>>>(
            G3, (size_t)M * 512, sk3, w_sf3, 512, nullptr, s12);

        final_kernel<<<NB, 64, 0, stream>>>(s12, W_out, b_out, out);
    } else {
        // ---------------- legacy fp32 path (round-3) ----------------
        float* y7  = (float*)d_ws;
        float* z1  = y7 + (size_t)M * 512;
        float* z2p = z1 + (size_t)M * 2048;
        float* z3p = z1;
        size_t need2 = ((size_t)M * 512 + (size_t)M * 2048 + 2 * (size_t)M * 1024) * 4;
        const int ksplit2 = (ws_size >= need2) ? 2 : 1;

        front_kernel<<<NB * CC / 256, 256, 0, stream>>>(
            x, w_jeff, w_cc, w_sf0, w_sf1, nullptr, y7);
        gemm_nt<<<dim3(2048 / 64, 2048 / 64, 1), 256, 0, stream>>>(
            y7, W1, z1, M, 2048, 512, 512);
        if_filter_kernel<<<NB * 2048 / 256, 256, 0, stream>>>(z1, 0, 1, w_sf2, 2048);
        gemm_nt<<<dim3(1024 / 64, 2048 / 64, ksplit2), 256, 0, stream>>>(
            z1, W2, z2p, M, 1024, 2048, 2048 / ksplit2);
        if_filter_kernel<<<NB * 1024 / 256, 256, 0, stream>>>(
            z2p, (size_t)M * 1024, ksplit2, w_sf3, 1024);
        gemm_nt<<<dim3(512 / 64, 2048 / 64, 4), 256, 0, stream>>>(
            z2p, W3, z3p, M, 512, 1024, 1024 / 4);
        if_filter_kernel<<<NB * 512 / 256, 256, 0, stream>>>(
            z3p, (size_t)M * 512, 4, nullptr, 512);
        final_kernel<<<NB, 64, 0, stream>>>(z3p, W_out, b_out, out);
    }
}

// Round 8
// 321.944 us; speedup vs baseline: 1.2540x; 1.0233x over previous
//
#include <hip/hip_runtime.h>
#include <math.h>

#define T_STEPS 32
#define NB 64      // batch
#define CC 512     // channels
#define AA 32      // cc_acc size
#define MROWS (T_STEPS * NB)   // 2048 GEMM rows

typedef __attribute__((ext_vector_type(8)))  short bf16x8;
typedef __attribute__((ext_vector_type(16))) float f32x16;

__device__ __forceinline__ float sig_decay(const float* wp) {
    return 1.0f - 1.0f / (1.0f + expf(-wp[0]));   // 1 - sigmoid(w)
}

__device__ __forceinline__ unsigned short f2bf_rne(float f) {
    unsigned int u = __float_as_uint(f);
    u += 0x7FFF + ((u >> 16) & 1);
    return (unsigned short)(u >> 16);
}

// ===========================================================================
// Packed-operand layouts (all verified equivalent to the round-5/7 passing
// fragment semantics for v_mfma_f32_32x32x16_bf16):
//   A/B fragment chunk (16 B = 8 bf16): lane L holds row r = (L&31) of a
//   32-row tile, k = 8*(L>>5) + j (j = byte pos).  Chunk index:
//     A: (mt*KS + ks)*64 + L          mt = m>>5, ks = k>>4, KS = K/16
//     B: ((p*NT + nt)*KS + ks)*64 + L nt = n>>5, NT = N/32, p = plane
//   C tile (32x32 fp32, row-major): idx = (mt*NT + nt)*1024 + row*32 + col
// ===========================================================================

// ---------------------------------------------------------------------------
// Split fp32 weights into 3 bf16 planes AND pack into B-fragment order.
// Residual ~2^-27|w|; binary spike A keeps each MFMA product exact.
// ---------------------------------------------------------------------------
__global__ __launch_bounds__(256) void pack_b_kernel(
    const float* __restrict__ W, unsigned short* __restrict__ out,
    int Nw, int Kw, int kshift)
{
    int i = blockIdx.x * 256 + threadIdx.x;
    int n = i >> kshift;
    int k = i & (Kw - 1);
    if (n >= Nw) return;
    float w = W[i];
    unsigned short h = f2bf_rne(w);
    float fh = __uint_as_float((unsigned int)h << 16);
    float r = w - fh;
    unsigned short m = f2bf_rne(r);
    float fm = __uint_as_float((unsigned int)m << 16);
    unsigned short l = f2bf_rne(r - fm);
    unsigned short vals[3] = {h, m, l};
    const int NT = Nw >> 5, KS = Kw >> 4;
    int L = (n & 31) + 32 * ((k >> 3) & 1);
#pragma unroll
    for (int p = 0; p < 3; p++) {
        size_t chunk = ((size_t)(p * NT + (n >> 5)) * KS + (k >> 4)) * 64 + L;
        out[chunk * 8 + (k & 7)] = vals[p];
    }
}

// ---------------------------------------------------------------------------
// Front end (transpose + synapse tau=2 + jeffress + LIF + sf0 + w_cc + IF).
// spike_out != null: write IF spikes in packed A-fragment order (K = 512).
// Else legacy: apply sf1 filter, write plain fp32.
// ---------------------------------------------------------------------------
__global__ __launch_bounds__(256) void front_kernel(
    const float* __restrict__ x, const float* __restrict__ w_jeff,
    const float* __restrict__ w_cc, const float* __restrict__ w_sf0,
    const float* __restrict__ w_sf1,
    unsigned short* __restrict__ spike_out, float* __restrict__ filt_out)
{
    __shared__ float wj[2 * AA];
    __shared__ float wcc[AA];
    int tid = threadIdx.x;
    if (tid < 2 * AA) wj[tid] = w_jeff[tid];
    if (tid < AA) wcc[tid] = w_cc[tid];
    __syncthreads();

    int g = blockIdx.x * 256 + tid;     // n*CC + c
    int n = g >> 9;
    int c = g & (CC - 1);

    const float inv_lif = 1.0f / 1.5f;
    float d0 = sig_decay(w_sf0);
    float d1 = sig_decay(w_sf1);

    float s0 = 0.f, s1 = 0.f, v6 = 0.f, u1 = 0.f;
    float v[AA], u[AA];
#pragma unroll
    for (int a = 0; a < AA; a++) { v[a] = 0.f; u[a] = 0.f; }

    // packed-A address pieces (m = t*64+n, k = c, K = 512 -> KS = 32)
    const int pL = (n & 31) + 32 * ((c >> 3) & 1);
    const int pks = c >> 4;
    const int pj = c & 7;

    for (int t = 0; t < T_STEPS; t++) {
        const float* xp = x + (size_t)((t * NB + n) * 2) * CC + c;
        s0 = s0 * 0.5f + xp[0];
        s1 = s1 * 0.5f + xp[CC];
        float acc = 0.f;
#pragma unroll
        for (int a = 0; a < AA; a++) {
            float z  = wj[2 * a] * s0 + wj[2 * a + 1] * s1;
            float vv = v[a] + (z - v[a]) * inv_lif;
            bool  sp = vv >= 1.0f;
            v[a] = sp ? 0.0f : vv;
            float uu = u[a] * d0 + (sp ? 1.0f : 0.0f);
            u[a] = uu;
            acc += wcc[a] * uu;
        }
        v6 += acc;
        bool sp6 = v6 >= 1.0f;
        v6 = sp6 ? 0.0f : v6;
        if (spike_out) {
            int mt = (t * NB + n) >> 5;
            size_t adr = (((size_t)mt * 32 + pks) * 64 + pL) * 8 + pj;
            spike_out[adr] = sp6 ? (unsigned short)0x3F80 : (unsigned short)0;
        } else {
            u1 = u1 * d1 + (sp6 ? 1.0f : 0.0f);
            filt_out[(size_t)(t * NB + n) * CC + c] = u1;
        }
    }
}

// ---------------------------------------------------------------------------
// Consumer: sum split-K parts of tiled G (fixed order), commuted filter,
// IF, emit spikes (packed-A bf16 for next GEMM, or plain fp32).
// ---------------------------------------------------------------------------
__global__ __launch_bounds__(256) void if_spike_kernel(
    const float* __restrict__ G, size_t partStride, int nparts,
    const float* __restrict__ w_sf_in, int F, int fshift,
    unsigned short* __restrict__ out_bf, float* __restrict__ out_f32)
{
    int tid = blockIdx.x * 256 + threadIdx.x;
    int n = tid >> fshift;
    int f = tid & (F - 1);
    const int NT = F >> 5;
    const int NF = NB * F;
    float dz = sig_decay(w_sf_in);
    float zf = 0.f, v = 0.f;
    const int pL = (n & 31) + 32 * ((f >> 3) & 1);
    const int KS = F >> 4;
    for (int t = 0; t < T_STEPS; t++) {
        int mt = 2 * t + (n >> 5);
        size_t roff = ((size_t)mt * NT + (f >> 5)) * 1024 + (n & 31) * 32 + (f & 31);
        float gsum = G[roff];
        for (int p = 1; p < nparts; p++) gsum += G[p * partStride + roff];
        zf = zf * dz + gsum;      // commuted synapse filter
        v += zf;                  // IF
        bool sp = v >= 1.0f;
        v = sp ? 0.0f : v;
        if (out_bf) {
            size_t adr = (((size_t)mt * KS + (f >> 4)) * 64 + pL) * 8 + (f & 7);
            out_bf[adr] = sp ? (unsigned short)0x3F80 : (unsigned short)0;
        } else {
            out_f32[(size_t)t * NF + tid] = sp ? 1.0f : 0.0f;
        }
    }
}

// ---------------------------------------------------------------------------
// Binary-A bf16 MFMA GEMM, packed operands, software-pipelined.
// Block: 512 threads = 8 waves; block tile 128m x 256n; wave = 128m x 32n.
// BK = 16 per stage; LDS double buffer 2 x 28 KB.  Per stage per wave:
// 7 ds_read_b128 (4 A + 3 B planes) feeding 12 MFMAs; reads for stage k+1
// are issued one full stage ahead; global loads two stages ahead; ONE
// barrier per stage.  C written in 32x32 tiles (coalesced 128-B rows).
// ---------------------------------------------------------------------------
__global__ __launch_bounds__(512, 2) void bgemm(
    const unsigned short* __restrict__ Ap,   // packed spikes (M x K)
    const unsigned short* __restrict__ Bp,   // packed 3-plane weights
    float* __restrict__ C,                   // sk partials, tiled
    int N, int K_total, int K_per)
{
    const int NT = N >> 5, KS = K_total >> 4;
    __shared__ uint4 sh[2][1792];            // 2 x 28 KB

    const int tid = threadIdx.x;
    const int wv  = tid >> 6;                // 0..7  (n-tile of this wave)
    const int L   = tid & 63;
    const int bm32 = blockIdx.x * 4;         // m-tile base (128 m)
    const int bn32 = blockIdx.y * 8;         // n-tile base (256 n)
    const int ks0  = (blockIdx.z * K_per) >> 4;
    const int nk   = K_per >> 4;

    f32x16 acc[4];
#pragma unroll
    for (int i = 0; i < 4; i++)
#pragma unroll
        for (int r = 0; r < 16; r++) acc[i][r] = 0.f;

    const uint4* A4 = (const uint4*)Ap;
    const uint4* B4 = (const uint4*)Bp;
    const int ntl = tid >> 6;                // staging B n-tile (0..7)
    const int cL  = tid & 63;

    uint4 pa, pb0, pb1, pb2;
    auto gload = [&](int ks) {
        if (tid < 256)
            pa = A4[((size_t)(bm32 + (tid >> 6)) * KS + ks) * 64 + (tid & 63)];
        pb0 = B4[((size_t)(0 * NT + bn32 + ntl) * KS + ks) * 64 + cL];
        pb1 = B4[((size_t)(1 * NT + bn32 + ntl) * KS + ks) * 64 + cL];
        pb2 = B4[((size_t)(2 * NT + bn32 + ntl) * KS + ks) * 64 + cL];
    };
    auto lwrite = [&](int b) {
        if (tid < 256) sh[b][tid] = pa;
        sh[b][256 + tid] = pb0;
        sh[b][256 + 512 + tid] = pb1;
        sh[b][256 + 1024 + tid] = pb2;
    };

    bf16x8 af[4], bf[3];
    auto rfrags = [&](int b) {
#pragma unroll
        for (int i = 0; i < 4; i++)
            af[i] = *(const bf16x8*)&sh[b][i * 64 + L];
#pragma unroll
        for (int p = 0; p < 3; p++)
            bf[p] = *(const bf16x8*)&sh[b][256 + (p * 8 + wv) * 64 + L];
    };

    gload(ks0);
    lwrite(0);
    if (nk > 1) gload(ks0 + 1);
    __syncthreads();
    rfrags(0);

    for (int kt = 0; kt < nk; kt++) {
        if (kt + 1 < nk) lwrite((kt + 1) & 1);      // stage k+1 -> other buf
        if (kt + 2 < nk) gload(ks0 + kt + 2);       // stage k+2 -> regs
#pragma unroll
        for (int p = 0; p < 3; p++)
#pragma unroll
            for (int i = 0; i < 4; i++)
                acc[i] = __builtin_amdgcn_mfma_f32_32x32x16_bf16(
                    af[i], bf[p], acc[i], 0, 0, 0);
        if (kt + 1 < nk) {
            __syncthreads();                        // buf (k+1) ready
            rfrags((kt + 1) & 1);                   // reads wait-free till next mfma
        }
    }

    // C write: 32x32 row-major tiles.  Layout (m74/m101-verified):
    // col = lane&31, row = (r&3) + 8*(r>>2) + 4*(lane>>5)
    float* Cp = C + (size_t)blockIdx.z * ((size_t)MROWS * N);
    const int col = L & 31, rbase = 4 * (L >> 5);
#pragma unroll
    for (int i = 0; i < 4; i++) {
        size_t tb = ((size_t)(bm32 + i) * NT + (bn32 + wv)) * 1024;
#pragma unroll
        for (int r = 0; r < 16; r++) {
            int row = (r & 3) + 8 * (r >> 2) + rbase;
            Cp[tb + row * 32 + col] = acc[i][r];
        }
    }
}

// ---------------------------------------------------------------------------
// Legacy fp32 path (round-3, proven) for small workspace.
// ---------------------------------------------------------------------------
__global__ __launch_bounds__(256) void if_filter_kernel(
    float* __restrict__ buf, size_t partStride, int nparts,
    const float* __restrict__ w_sf, int F)
{
    int tid = blockIdx.x * 256 + threadIdx.x;
    const int NF = NB * F;
    bool  filt = (w_sf != nullptr);
    float d = filt ? sig_decay(w_sf) : 0.0f;
    float v = 0.f, u = 0.f;
    for (int t = 0; t < T_STEPS; t++) {
        size_t off = (size_t)t * NF + tid;
        float zt = buf[off];
        for (int p = 1; p < nparts; p++) zt += buf[p * partStride + off];
        v += zt;
        bool sp = v >= 1.0f;
        v = sp ? 0.0f : v;
        float s = sp ? 1.0f : 0.0f;
        if (filt) { u = u * d + s; buf[off] = u; }
        else      { buf[off] = s; }
    }
}

__global__ __launch_bounds__(256) void gemm_nt(
    const float* __restrict__ A, const float* __restrict__ B,
    float* __restrict__ C, int M, int N, int K_total, int K_per)
{
    constexpr int BM = 64, BN = 64, BK = 32;
    __shared__ float As[BK][BM + 4];
    __shared__ float Bs[BK][BN + 4];
    const int tid = threadIdx.x;
    const int tx  = tid & 15;
    const int ty  = tid >> 4;
    const int bm  = blockIdx.y * BM;
    const int bn  = blockIdx.x * BN;
    const int kbeg = blockIdx.z * K_per;
    float acc[4][4];
#pragma unroll
    for (int i = 0; i < 4; i++)
#pragma unroll
        for (int j = 0; j < 4; j++) acc[i][j] = 0.f;
    const int lrow = tid >> 3;
    const int lkq  = tid & 7;
    for (int kt = 0; kt < K_per; kt += BK) {
        int k0 = kbeg + kt;
        __syncthreads();
#pragma unroll
        for (int i = 0; i < 2; i++) {
            int row = lrow + i * 32;
            float4 av = *(const float4*)(A + (size_t)(bm + row) * K_total + k0 + lkq * 4);
            As[lkq * 4 + 0][row] = av.x;
            As[lkq * 4 + 1][row] = av.y;
            As[lkq * 4 + 2][row] = av.z;
            As[lkq * 4 + 3][row] = av.w;
            float4 bv = *(const float4*)(B + (size_t)(bn + row) * K_total + k0 + lkq * 4);
            Bs[lkq * 4 + 0][row] = bv.x;
            Bs[lkq * 4 + 1][row] = bv.y;
            Bs[lkq * 4 + 2][row] = bv.z;
            Bs[lkq * 4 + 3][row] = bv.w;
        }
        __syncthreads();
#pragma unroll
        for (int kk = 0; kk < BK; kk++) {
            float4 a0 = *(const float4*)&As[kk][ty * 4];
            float4 b0 = *(const float4*)&Bs[kk][tx * 4];
            float ar[4] = {a0.x, a0.y, a0.z, a0.w};
            float br[4] = {b0.x, b0.y, b0.z, b0.w};
#pragma unroll
            for (int i = 0; i < 4; i++)
#pragma unroll
                for (int j = 0; j < 4; j++) acc[i][j] += ar[i] * br[j];
        }
    }
    float* Cp = C + (size_t)blockIdx.z * (size_t)M * N;
#pragma unroll
    for (int i = 0; i < 4; i++) {
        float4 o;
        o.x = acc[i][0]; o.y = acc[i][1]; o.z = acc[i][2]; o.w = acc[i][3];
        *(float4*)(Cp + (size_t)(bm + ty * 4 + i) * N + bn + tx * 4) = o;
    }
}

// ---------------------------------------------------------------------------
// Final: out[t,n] = cumsum_t( dot(s3[t,n,:512], W_out) + b ).  One wave per n.
// ---------------------------------------------------------------------------
__global__ __launch_bounds__(64) void final_kernel(
    const float* __restrict__ y15, const float* __restrict__ W_out,
    const float* __restrict__ b_out, float* __restrict__ out)
{
    int n = blockIdx.x;
    int lane = threadIdx.x;
    float w[8];
#pragma unroll
    for (int j = 0; j < 8; j++) w[j] = W_out[lane + j * 64];
    float b = b_out[0];
    float cum = 0.f;
    for (int t = 0; t < T_STEPS; t++) {
        const float* yp = y15 + (size_t)(t * NB + n) * 512;
        float p = 0.f;
#pragma unroll
        for (int j = 0; j < 8; j++) p += yp[lane + j * 64] * w[j];
#pragma unroll
        for (int off = 32; off > 0; off >>= 1) p += __shfl_down(p, off);
        if (lane == 0) {
            cum += p + b;
            out[t * NB + n] = cum;
        }
    }
}

extern "C" void kernel_launch(void* const* d_in, const int* in_sizes, int n_in,
                              void* d_out, int out_size, void* d_ws, size_t ws_size,
                              hipStream_t stream) {
    (void)in_sizes; (void)n_in; (void)out_size;
    const float* x      = (const float*)d_in[0];
    const float* w_jeff = (const float*)d_in[1];
    const float* w_cc   = (const float*)d_in[2];
    const float* w_sf0  = (const float*)d_in[3];
    const float* W1     = (const float*)d_in[4];
    const float* w_sf1  = (const float*)d_in[5];
    const float* W2     = (const float*)d_in[6];
    const float* w_sf2  = (const float*)d_in[7];
    const float* W3     = (const float*)d_in[8];
    const float* w_sf3  = (const float*)d_in[9];
    const float* W_out  = (const float*)d_in[10];
    const float* b_out  = (const float*)d_in[11];
    float* out = (float*)d_out;
    const int M = MROWS;   // 2048

    const size_t nW1 = (size_t)2048 * 512, nW2 = (size_t)1024 * 2048, nW3 = (size_t)512 * 1024;
    // ws layout: Bp1|Bp2|Bp3 (3 planes each, packed) | s6 | G(32 MB shared) |
    //            s8 | s10 | s12
    size_t need = 3 * (nW1 + nW2 + nW3) * 2     // packed planes   21 MB
                + (size_t)M * 512 * 2           // s6 packed        2 MB
                + (size_t)2 * M * 2048 * 4      // G shared region 32 MB
                + (size_t)M * 2048 * 2          // s8               8 MB
                + (size_t)M * 1024 * 2          // s10              4 MB
                + (size_t)M * 512 * 4;          // s12              4 MB

    if (ws_size >= need) {
        unsigned short* Bp1 = (unsigned short*)d_ws;
        unsigned short* Bp2 = Bp1 + 3 * nW1;
        unsigned short* Bp3 = Bp2 + 3 * nW2;
        unsigned short* s6  = Bp3 + 3 * nW3;
        float* G   = (float*)(s6 + (size_t)M * 512);          // 2*M*2048 floats
        unsigned short* s8  = (unsigned short*)(G + (size_t)2 * M * 2048);
        unsigned short* s10 = s8 + (size_t)M * 2048;
        float* s12 = (float*)(s10 + (size_t)M * 1024);

        pack_b_kernel<<<(int)(nW1 / 256), 256, 0, stream>>>(W1, Bp1, 2048, 512, 9);
        pack_b_kernel<<<(int)(nW2 / 256), 256, 0, stream>>>(W2, Bp2, 1024, 2048, 11);
        pack_b_kernel<<<(int)(nW3 / 256), 256, 0, stream>>>(W3, Bp3, 512, 1024, 10);

        front_kernel<<<NB * CC / 256, 256, 0, stream>>>(
            x, w_jeff, w_cc, w_sf0, w_sf1, s6, nullptr);

        // GEMM1: N=2048, K=512, sk=2.  grid(m16, n8, sk2) = 256 blocks
        bgemm<<<dim3(16, 8, 2), 512, 0, stream>>>(s6, Bp1, G, 2048, 512, 256);
        if_spike_kernel<<<NB * 2048 / 256, 256, 0, stream>>>(
            G, (size_t)M * 2048, 2, w_sf1, 2048, 11, s8, nullptr);

        // GEMM2: N=1024, K=2048, sk=4.  grid(16, 4, 4) = 256 blocks
        bgemm<<<dim3(16, 4, 4), 512, 0, stream>>>(s8, Bp2, G, 1024, 2048, 512);
        if_spike_kernel<<<NB * 1024 / 256, 256, 0, stream>>>(
            G, (size_t)M * 1024, 4, w_sf2, 1024, 10, s10, nullptr);

        // GEMM3: N=512, K=1024, sk=8.  grid(16, 2, 8) = 256 blocks
        bgemm<<<dim3(16, 2, 8), 512, 0, stream>>>(s10, Bp3, G, 512, 1024, 128);
        if_spike_kernel<<<NB * 512 / 256, 256, 0, stream>>>(
            G, (size_t)M * 512, 8, w_sf3, 512, 9, nullptr, s12);

        final_kernel<<<NB, 64, 0, stream>>>(s12, W_out, b_out, out);
    } else {
        // ---------------- legacy fp32 path (round-3) ----------------
        float* y7  = (float*)d_ws;
        float* z1  = y7 + (size_t)M * 512;
        float* z2p = z1 + (size_t)M * 2048;
        float* z3p = z1;
        size_t need2 = ((size_t)M * 512 + (size_t)M * 2048 + 2 * (size_t)M * 1024) * 4;
        const int ksplit2 = (ws_size >= need2) ? 2 : 1;

        front_kernel<<<NB * CC / 256, 256, 0, stream>>>(
            x, w_jeff, w_cc, w_sf0, w_sf1, nullptr, y7);
        gemm_nt<<<dim3(2048 / 64, 2048 / 64, 1), 256, 0, stream>>>(
            y7, W1, z1, M, 2048, 512, 512);
        if_filter_kernel<<<NB * 2048 / 256, 256, 0, stream>>>(z1, 0, 1, w_sf2, 2048);
        gemm_nt<<<dim3(1024 / 64, 2048 / 64, ksplit2), 256, 0, stream>>>(
            z1, W2, z2p, M, 1024, 2048, 2048 / ksplit2);
        if_filter_kernel<<<NB * 1024 / 256, 256, 0, stream>>>(
            z2p, (size_t)M * 1024, ksplit2, w_sf3, 1024);
        gemm_nt<<<dim3(512 / 64, 2048 / 64, 4), 256, 0, stream>>>(
            z2p, W3, z3p, M, 512, 1024, 1024 / 4);
        if_filter_kernel<<<NB * 512 / 256, 256, 0, stream>>>(
            z3p, (size_t)M * 512, 4, nullptr, 512);
        final_kernel<<<NB, 64, 0, stream>>>(z3p, W_out, b_out, out);
    }
}

// Round 9
// 301.854 us; speedup vs baseline: 1.3374x; 1.0666x over previous
//
#include <hip/hip_runtime.h>
#include <math.h>

#define T_STEPS 32
#define NB 64      // batch
#define CC 512     // channels
#define AA 32      // cc_acc size
#define MROWS (T_STEPS * NB)   // 2048 GEMM rows

typedef __attribute__((ext_vector_type(8)))  short bf16x8;
typedef __attribute__((ext_vector_type(16))) float f32x16;

__device__ __forceinline__ float sig_decay(const float* wp) {
    return 1.0f - 1.0f / (1.0f + expf(-wp[0]));   // 1 - sigmoid(w)
}

__device__ __forceinline__ unsigned short f2bf_rne(float f) {
    unsigned int u = __float_as_uint(f);
    u += 0x7FFF + ((u >> 16) & 1);
    return (unsigned short)(u >> 16);
}

// ===========================================================================
// Packed-operand layouts (verified by rounds 5-8 passing runs):
//   A/B fragment chunk (16 B = 8 bf16): lane L holds row r = (L&31) of a
//   32-row tile, k = 8*(L>>5) + j.  Chunk index:
//     A: (mt*KS + ks)*64 + L          mt = m>>5, ks = k>>4, KS = K/16
//     B: ((p*NT + nt)*KS + ks)*64 + L nt = n>>5, NT = N/32, p = plane
//   C tile (32x32 fp32, row-major): idx = (mt*NT + nt)*1024 + row*32 + col
// ===========================================================================

// ---------------------------------------------------------------------------
// Split fp32 weights into 3 bf16 planes AND pack into B-fragment order.
// ---------------------------------------------------------------------------
__global__ __launch_bounds__(256) void pack_b_kernel(
    const float* __restrict__ W, unsigned short* __restrict__ out,
    int Nw, int Kw, int kshift)
{
    int i = blockIdx.x * 256 + threadIdx.x;
    int n = i >> kshift;
    int k = i & (Kw - 1);
    if (n >= Nw) return;
    float w = W[i];
    unsigned short h = f2bf_rne(w);
    float fh = __uint_as_float((unsigned int)h << 16);
    float r = w - fh;
    unsigned short m = f2bf_rne(r);
    float fm = __uint_as_float((unsigned int)m << 16);
    unsigned short l = f2bf_rne(r - fm);
    unsigned short vals[3] = {h, m, l};
    const int NT = Nw >> 5, KS = Kw >> 4;
    int L = (n & 31) + 32 * ((k >> 3) & 1);
#pragma unroll
    for (int p = 0; p < 3; p++) {
        size_t chunk = ((size_t)(p * NT + (n >> 5)) * KS + (k >> 4)) * 64 + L;
        out[chunk * 8 + (k & 7)] = vals[p];
    }
}

// ---------------------------------------------------------------------------
// Front end (transpose + synapse tau=2 + jeffress + LIF + sf0 + w_cc + IF).
// spike_out != null: write IF spikes in packed A-fragment order (K = 512).
// ---------------------------------------------------------------------------
__global__ __launch_bounds__(256) void front_kernel(
    const float* __restrict__ x, const float* __restrict__ w_jeff,
    const float* __restrict__ w_cc, const float* __restrict__ w_sf0,
    const float* __restrict__ w_sf1,
    unsigned short* __restrict__ spike_out, float* __restrict__ filt_out)
{
    __shared__ float wj[2 * AA];
    __shared__ float wcc[AA];
    int tid = threadIdx.x;
    if (tid < 2 * AA) wj[tid] = w_jeff[tid];
    if (tid < AA) wcc[tid] = w_cc[tid];
    __syncthreads();

    int g = blockIdx.x * 256 + tid;     // n*CC + c
    int n = g >> 9;
    int c = g & (CC - 1);

    const float inv_lif = 1.0f / 1.5f;
    float d0 = sig_decay(w_sf0);
    float d1 = sig_decay(w_sf1);

    float s0 = 0.f, s1 = 0.f, v6 = 0.f, u1 = 0.f;
    float v[AA], u[AA];
#pragma unroll
    for (int a = 0; a < AA; a++) { v[a] = 0.f; u[a] = 0.f; }

    const int pL = (n & 31) + 32 * ((c >> 3) & 1);
    const int pks = c >> 4;
    const int pj = c & 7;

    for (int t = 0; t < T_STEPS; t++) {
        const float* xp = x + (size_t)((t * NB + n) * 2) * CC + c;
        s0 = s0 * 0.5f + xp[0];
        s1 = s1 * 0.5f + xp[CC];
        float acc = 0.f;
#pragma unroll
        for (int a = 0; a < AA; a++) {
            float z  = wj[2 * a] * s0 + wj[2 * a + 1] * s1;
            float vv = v[a] + (z - v[a]) * inv_lif;
            bool  sp = vv >= 1.0f;
            v[a] = sp ? 0.0f : vv;
            float uu = u[a] * d0 + (sp ? 1.0f : 0.0f);
            u[a] = uu;
            acc += wcc[a] * uu;
        }
        v6 += acc;
        bool sp6 = v6 >= 1.0f;
        v6 = sp6 ? 0.0f : v6;
        if (spike_out) {
            int mt = (t * NB + n) >> 5;
            size_t adr = (((size_t)mt * 32 + pks) * 64 + pL) * 8 + pj;
            spike_out[adr] = sp6 ? (unsigned short)0x3F80 : (unsigned short)0;
        } else {
            u1 = u1 * d1 + (sp6 ? 1.0f : 0.0f);
            filt_out[(size_t)(t * NB + n) * CC + c] = u1;
        }
    }
}

// ---------------------------------------------------------------------------
// Consumer: sum NPARTS split-K parts of tiled G (fixed order, templated +
// fully unrolled so ALL loads are independent and stream at full BW),
// then run the serial filter+IF recurrence on registers, emit spikes.
// ---------------------------------------------------------------------------
template <int NPARTS>
__global__ __launch_bounds__(64) void if_spike_kernel(
    const float* __restrict__ G, size_t partStride,
    const float* __restrict__ w_sf_in, int F, int fshift,
    unsigned short* __restrict__ out_bf, float* __restrict__ out_f32)
{
    int gid = blockIdx.x * 64 + threadIdx.x;   // n*F + f
    int n = gid >> fshift;
    int f = gid & (F - 1);
    const int NT = F >> 5;
    const int NF = NB * F;
    float dz = sig_decay(w_sf_in);

    // G tile offset for step t: ((2t + n>>5)*NT + f>>5)*1024 + (n&31)*32 + (f&31)
    size_t base = ((size_t)(n >> 5) * NT + (f >> 5)) * 1024
                + (size_t)(n & 31) * 32 + (f & 31);
    const size_t tstride = (size_t)2 * NT * 1024;

    float gs[T_STEPS];
#pragma unroll
    for (int t = 0; t < T_STEPS; t++)
        gs[t] = G[base + (size_t)t * tstride];
#pragma unroll
    for (int p = 1; p < NPARTS; p++)
#pragma unroll
        for (int t = 0; t < T_STEPS; t++)
            gs[t] += G[(size_t)p * partStride + base + (size_t)t * tstride];

    float zf = 0.f, v = 0.f;
    const int pL = (n & 31) + 32 * ((f >> 3) & 1);
    const int KS = F >> 4;
    if (out_bf) {
#pragma unroll
        for (int t = 0; t < T_STEPS; t++) {
            zf = zf * dz + gs[t];     // commuted synapse filter
            v += zf;                  // IF
            bool sp = v >= 1.0f;
            v = sp ? 0.0f : v;
            int mt = 2 * t + (n >> 5);
            size_t adr = (((size_t)mt * KS + (f >> 4)) * 64 + pL) * 8 + (f & 7);
            out_bf[adr] = sp ? (unsigned short)0x3F80 : (unsigned short)0;
        }
    } else {
#pragma unroll
        for (int t = 0; t < T_STEPS; t++) {
            zf = zf * dz + gs[t];
            v += zf;
            bool sp = v >= 1.0f;
            v = sp ? 0.0f : v;
            out_f32[(size_t)t * NF + gid] = sp ? 1.0f : 0.0f;
        }
    }
}

// ---------------------------------------------------------------------------
// Binary-A bf16 MFMA GEMM, packed operands, software-pipelined (round 8).
// ---------------------------------------------------------------------------
__global__ __launch_bounds__(512, 2) void bgemm(
    const unsigned short* __restrict__ Ap,   // packed spikes (M x K)
    const unsigned short* __restrict__ Bp,   // packed 3-plane weights
    float* __restrict__ C,                   // sk partials, tiled
    int N, int K_total, int K_per)
{
    const int NT = N >> 5, KS = K_total >> 4;
    __shared__ uint4 sh[2][1792];            // 2 x 28 KB

    const int tid = threadIdx.x;
    const int wv  = tid >> 6;                // 0..7  (n-tile of this wave)
    const int L   = tid & 63;
    const int bm32 = blockIdx.x * 4;         // m-tile base (128 m)
    const int bn32 = blockIdx.y * 8;         // n-tile base (256 n)
    const int ks0  = (blockIdx.z * K_per) >> 4;
    const int nk   = K_per >> 4;

    f32x16 acc[4];
#pragma unroll
    for (int i = 0; i < 4; i++)
#pragma unroll
        for (int r = 0; r < 16; r++) acc[i][r] = 0.f;

    const uint4* A4 = (const uint4*)Ap;
    const uint4* B4 = (const uint4*)Bp;
    const int ntl = tid >> 6;
    const int cL  = tid & 63;

    uint4 pa, pb0, pb1, pb2;
    auto gload = [&](int ks) {
        if (tid < 256)
            pa = A4[((size_t)(bm32 + (tid >> 6)) * KS + ks) * 64 + (tid & 63)];
        pb0 = B4[((size_t)(0 * NT + bn32 + ntl) * KS + ks) * 64 + cL];
        pb1 = B4[((size_t)(1 * NT + bn32 + ntl) * KS + ks) * 64 + cL];
        pb2 = B4[((size_t)(2 * NT + bn32 + ntl) * KS + ks) * 64 + cL];
    };
    auto lwrite = [&](int b) {
        if (tid < 256) sh[b][tid] = pa;
        sh[b][256 + tid] = pb0;
        sh[b][256 + 512 + tid] = pb1;
        sh[b][256 + 1024 + tid] = pb2;
    };

    bf16x8 af[4], bf[3];
    auto rfrags = [&](int b) {
#pragma unroll
        for (int i = 0; i < 4; i++)
            af[i] = *(const bf16x8*)&sh[b][i * 64 + L];
#pragma unroll
        for (int p = 0; p < 3; p++)
            bf[p] = *(const bf16x8*)&sh[b][256 + (p * 8 + wv) * 64 + L];
    };

    gload(ks0);
    lwrite(0);
    if (nk > 1) gload(ks0 + 1);
    __syncthreads();
    rfrags(0);

    for (int kt = 0; kt < nk; kt++) {
        if (kt + 1 < nk) lwrite((kt + 1) & 1);      // stage k+1 -> other buf
        if (kt + 2 < nk) gload(ks0 + kt + 2);       // stage k+2 -> regs
#pragma unroll
        for (int p = 0; p < 3; p++)
#pragma unroll
            for (int i = 0; i < 4; i++)
                acc[i] = __builtin_amdgcn_mfma_f32_32x32x16_bf16(
                    af[i], bf[p], acc[i], 0, 0, 0);
        if (kt + 1 < nk) {
            __syncthreads();
            rfrags((kt + 1) & 1);
        }
    }

    // C write: 32x32 row-major tiles.  col = lane&31, row = (r&3)+8*(r>>2)+4*(lane>>5)
    float* Cp = C + (size_t)blockIdx.z * ((size_t)MROWS * N);
    const int col = L & 31, rbase = 4 * (L >> 5);
#pragma unroll
    for (int i = 0; i < 4; i++) {
        size_t tb = ((size_t)(bm32 + i) * NT + (bn32 + wv)) * 1024;
#pragma unroll
        for (int r = 0; r < 16; r++) {
            int row = (r & 3) + 8 * (r >> 2) + rbase;
            Cp[tb + row * 32 + col] = acc[i][r];
        }
    }
}

// ---------------------------------------------------------------------------
// Legacy fp32 path (round-3, proven) for small workspace.
// ---------------------------------------------------------------------------
__global__ __launch_bounds__(256) void if_filter_kernel(
    float* __restrict__ buf, size_t partStride, int nparts,
    const float* __restrict__ w_sf, int F)
{
    int tid = blockIdx.x * 256 + threadIdx.x;
    const int NF = NB * F;
    bool  filt = (w_sf != nullptr);
    float d = filt ? sig_decay(w_sf) : 0.0f;
    float v = 0.f, u = 0.f;
    for (int t = 0; t < T_STEPS; t++) {
        size_t off = (size_t)t * NF + tid;
        float zt = buf[off];
        for (int p = 1; p < nparts; p++) zt += buf[p * partStride + off];
        v += zt;
        bool sp = v >= 1.0f;
        v = sp ? 0.0f : v;
        float s = sp ? 1.0f : 0.0f;
        if (filt) { u = u * d + s; buf[off] = u; }
        else      { buf[off] = s; }
    }
}

__global__ __launch_bounds__(256) void gemm_nt(
    const float* __restrict__ A, const float* __restrict__ B,
    float* __restrict__ C, int M, int N, int K_total, int K_per)
{
    constexpr int BM = 64, BN = 64, BK = 32;
    __shared__ float As[BK][BM + 4];
    __shared__ float Bs[BK][BN + 4];
    const int tid = threadIdx.x;
    const int tx  = tid & 15;
    const int ty  = tid >> 4;
    const int bm  = blockIdx.y * BM;
    const int bn  = blockIdx.x * BN;
    const int kbeg = blockIdx.z * K_per;
    float acc[4][4];
#pragma unroll
    for (int i = 0; i < 4; i++)
#pragma unroll
        for (int j = 0; j < 4; j++) acc[i][j] = 0.f;
    const int lrow = tid >> 3;
    const int lkq  = tid & 7;
    for (int kt = 0; kt < K_per; kt += BK) {
        int k0 = kbeg + kt;
        __syncthreads();
#pragma unroll
        for (int i = 0; i < 2; i++) {
            int row = lrow + i * 32;
            float4 av = *(const float4*)(A + (size_t)(bm + row) * K_total + k0 + lkq * 4);
            As[lkq * 4 + 0][row] = av.x;
            As[lkq * 4 + 1][row] = av.y;
            As[lkq * 4 + 2][row] = av.z;
            As[lkq * 4 + 3][row] = av.w;
            float4 bv = *(const float4*)(B + (size_t)(bn + row) * K_total + k0 + lkq * 4);
            Bs[lkq * 4 + 0][row] = bv.x;
            Bs[lkq * 4 + 1][row] = bv.y;
            Bs[lkq * 4 + 2][row] = bv.z;
            Bs[lkq * 4 + 3][row] = bv.w;
        }
        __syncthreads();
#pragma unroll
        for (int kk = 0; kk < BK; kk++) {
            float4 a0 = *(const float4*)&As[kk][ty * 4];
            float4 b0 = *(const float4*)&Bs[kk][tx * 4];
            float ar[4] = {a0.x, a0.y, a0.z, a0.w};
            float br[4] = {b0.x, b0.y, b0.z, b0.w};
#pragma unroll
            for (int i = 0; i < 4; i++)
#pragma unroll
                for (int j = 0; j < 4; j++) acc[i][j] += ar[i] * br[j];
        }
    }
    float* Cp = C + (size_t)blockIdx.z * (size_t)M * N;
#pragma unroll
    for (int i = 0; i < 4; i++) {
        float4 o;
        o.x = acc[i][0]; o.y = acc[i][1]; o.z = acc[i][2]; o.w = acc[i][3];
        *(float4*)(Cp + (size_t)(bm + ty * 4 + i) * N + bn + tx * 4) = o;
    }
}

// ---------------------------------------------------------------------------
// Final: out[t,n] = cumsum_t( dot(s3[t,n,:512], W_out) + b ).  One wave per n.
// ---------------------------------------------------------------------------
__global__ __launch_bounds__(64) void final_kernel(
    const float* __restrict__ y15, const float* __restrict__ W_out,
    const float* __restrict__ b_out, float* __restrict__ out)
{
    int n = blockIdx.x;
    int lane = threadIdx.x;
    float w[8];
#pragma unroll
    for (int j = 0; j < 8; j++) w[j] = W_out[lane + j * 64];
    float b = b_out[0];
    float cum = 0.f;
    for (int t = 0; t < T_STEPS; t++) {
        const float* yp = y15 + (size_t)(t * NB + n) * 512;
        float p = 0.f;
#pragma unroll
        for (int j = 0; j < 8; j++) p += yp[lane + j * 64] * w[j];
#pragma unroll
        for (int off = 32; off > 0; off >>= 1) p += __shfl_down(p, off);
        if (lane == 0) {
            cum += p + b;
            out[t * NB + n] = cum;
        }
    }
}

extern "C" void kernel_launch(void* const* d_in, const int* in_sizes, int n_in,
                              void* d_out, int out_size, void* d_ws, size_t ws_size,
                              hipStream_t stream) {
    (void)in_sizes; (void)n_in; (void)out_size;
    const float* x      = (const float*)d_in[0];
    const float* w_jeff = (const float*)d_in[1];
    const float* w_cc   = (const float*)d_in[2];
    const float* w_sf0  = (const float*)d_in[3];
    const float* W1     = (const float*)d_in[4];
    const float* w_sf1  = (const float*)d_in[5];
    const float* W2     = (const float*)d_in[6];
    const float* w_sf2  = (const float*)d_in[7];
    const float* W3     = (const float*)d_in[8];
    const float* w_sf3  = (const float*)d_in[9];
    const float* W_out  = (const float*)d_in[10];
    const float* b_out  = (const float*)d_in[11];
    float* out = (float*)d_out;
    const int M = MROWS;   // 2048

    const size_t nW1 = (size_t)2048 * 512, nW2 = (size_t)1024 * 2048, nW3 = (size_t)512 * 1024;
    size_t need = 3 * (nW1 + nW2 + nW3) * 2     // packed planes   21 MB
                + (size_t)M * 512 * 2           // s6 packed        2 MB
                + (size_t)2 * M * 2048 * 4      // G shared region 32 MB
                + (size_t)M * 2048 * 2          // s8               8 MB
                + (size_t)M * 1024 * 2          // s10              4 MB
                + (size_t)M * 512 * 4;          // s12              4 MB

    if (ws_size >= need) {
        unsigned short* Bp1 = (unsigned short*)d_ws;
        unsigned short* Bp2 = Bp1 + 3 * nW1;
        unsigned short* Bp3 = Bp2 + 3 * nW2;
        unsigned short* s6  = Bp3 + 3 * nW3;
        float* G   = (float*)(s6 + (size_t)M * 512);          // 2*M*2048 floats
        unsigned short* s8  = (unsigned short*)(G + (size_t)2 * M * 2048);
        unsigned short* s10 = s8 + (size_t)M * 2048;
        float* s12 = (float*)(s10 + (size_t)M * 1024);

        pack_b_kernel<<<(int)(nW1 / 256), 256, 0, stream>>>(W1, Bp1, 2048, 512, 9);
        pack_b_kernel<<<(int)(nW2 / 256), 256, 0, stream>>>(W2, Bp2, 1024, 2048, 11);
        pack_b_kernel<<<(int)(nW3 / 256), 256, 0, stream>>>(W3, Bp3, 512, 1024, 10);

        front_kernel<<<NB * CC / 256, 256, 0, stream>>>(
            x, w_jeff, w_cc, w_sf0, w_sf1, s6, nullptr);

        // GEMM1: N=2048, K=512, sk=2.  grid(m16, n8, sk2) = 256 blocks
        bgemm<<<dim3(16, 8, 2), 512, 0, stream>>>(s6, Bp1, G, 2048, 512, 256);
        if_spike_kernel<2><<<NB * 2048 / 64, 64, 0, stream>>>(
            G, (size_t)M * 2048, w_sf1, 2048, 11, s8, nullptr);

        // GEMM2: N=1024, K=2048, sk=4.  grid(16, 4, 4) = 256 blocks
        bgemm<<<dim3(16, 4, 4), 512, 0, stream>>>(s8, Bp2, G, 1024, 2048, 512);
        if_spike_kernel<4><<<NB * 1024 / 64, 64, 0, stream>>>(
            G, (size_t)M * 1024, w_sf2, 1024, 10, s10, nullptr);

        // GEMM3: N=512, K=1024, sk=8.  grid(16, 2, 8) = 256 blocks
        bgemm<<<dim3(16, 2, 8), 512, 0, stream>>>(s10, Bp3, G, 512, 1024, 128);
        if_spike_kernel<8><<<NB * 512 / 64, 64, 0, stream>>>(
            G, (size_t)M * 512, w_sf3, 512, 9, nullptr, s12);

        final_kernel<<<NB, 64, 0, stream>>>(s12, W_out, b_out, out);
    } else {
        // ---------------- legacy fp32 path (round-3) ----------------
        float* y7  = (float*)d_ws;
        float* z1  = y7 + (size_t)M * 512;
        float* z2p = z1 + (size_t)M * 2048;
        float* z3p = z1;
        size_t need2 = ((size_t)M * 512 + (size_t)M * 2048 + 2 * (size_t)M * 1024) * 4;
        const int ksplit2 = (ws_size >= need2) ? 2 : 1;

        front_kernel<<<NB * CC / 256, 256, 0, stream>>>(
            x, w_jeff, w_cc, w_sf0, w_sf1, nullptr, y7);
        gemm_nt<<<dim3(2048 / 64, 2048 / 64, 1), 256, 0, stream>>>(
            y7, W1, z1, M, 2048, 512, 512);
        if_filter_kernel<<<NB * 2048 / 256, 256, 0, stream>>>(z1, 0, 1, w_sf2, 2048);
        gemm_nt<<<dim3(1024 / 64, 2048 / 64, ksplit2), 256, 0, stream>>>(
            z1, W2, z2p, M, 1024, 2048, 2048 / ksplit2);
        if_filter_kernel<<<NB * 1024 / 256, 256, 0, stream>>>(
            z2p, (size_t)M * 1024, ksplit2, w_sf3, 1024);
        gemm_nt<<<dim3(512 / 64, 2048 / 64, 4), 256, 0, stream>>>(
            z2p, W3, z3p, M, 512, 1024, 1024 / 4);
        if_filter_kernel<<<NB * 512 / 256, 256, 0, stream>>>(
            z3p, (size_t)M * 512, 4, nullptr, 512);
        final_kernel<<<NB, 64, 0, stream>>>(z3p, W_out, b_out, out);
    }
}

// Round 10
// 246.188 us; speedup vs baseline: 1.6398x; 1.2261x over previous
//
#include <hip/hip_runtime.h>
#include <math.h>

#define T_STEPS 32
#define NB 64      // batch
#define CC 512     // channels
#define AA 32      // cc_acc size
#define MROWS (T_STEPS * NB)   // 2048 GEMM rows

typedef __attribute__((ext_vector_type(8)))  short bf16x8;
typedef __attribute__((ext_vector_type(16))) float f32x16;

__device__ __forceinline__ float sig_decay(const float* wp) {
    return 1.0f - 1.0f / (1.0f + expf(-wp[0]));   // 1 - sigmoid(w)
}

__device__ __forceinline__ unsigned short f2bf_rne(float f) {
    unsigned int u = __float_as_uint(f);
    u += 0x7FFF + ((u >> 16) & 1);
    return (unsigned short)(u >> 16);
}

// ===========================================================================
// Packed-operand layouts (verified by rounds 5-9 passing runs):
//   A/B fragment chunk (16 B = 8 bf16): lane L holds row r = (L&31) of a
//   32-row tile, k = 8*(L>>5) + j.  Chunk index:
//     A: (mt*KS + ks)*64 + L          mt = m>>5, ks = k>>4, KS = K/16
//     B: ((p*NT + nt)*KS + ks)*64 + L nt = n>>5, NT = N/32, p = plane
//   C tile (32x32 fp32, row-major): idx = (mt*NT + nt)*1024 + row*32 + col
// ===========================================================================

// ---------------------------------------------------------------------------
// Split fp32 weights into 3 bf16 planes AND pack into B-fragment order.
// ---------------------------------------------------------------------------
__global__ __launch_bounds__(256) void pack_b_kernel(
    const float* __restrict__ W, unsigned short* __restrict__ out,
    int Nw, int Kw, int kshift)
{
    int i = blockIdx.x * 256 + threadIdx.x;
    int n = i >> kshift;
    int k = i & (Kw - 1);
    if (n >= Nw) return;
    float w = W[i];
    unsigned short h = f2bf_rne(w);
    float fh = __uint_as_float((unsigned int)h << 16);
    float r = w - fh;
    unsigned short m = f2bf_rne(r);
    float fm = __uint_as_float((unsigned int)m << 16);
    unsigned short l = f2bf_rne(r - fm);
    unsigned short vals[3] = {h, m, l};
    const int NT = Nw >> 5, KS = Kw >> 4;
    int L = (n & 31) + 32 * ((k >> 3) & 1);
#pragma unroll
    for (int p = 0; p < 3; p++) {
        size_t chunk = ((size_t)(p * NT + (n >> 5)) * KS + (k >> 4)) * 64 + L;
        out[chunk * 8 + (k & 7)] = vals[p];
    }
}

// ---------------------------------------------------------------------------
// Front end (transpose + synapse tau=2 + jeffress + LIF + sf0 + w_cc + IF).
// spike_out != null: write IF spikes in packed A-fragment order (K = 512).
// ---------------------------------------------------------------------------
__global__ __launch_bounds__(256) void front_kernel(
    const float* __restrict__ x, const float* __restrict__ w_jeff,
    const float* __restrict__ w_cc, const float* __restrict__ w_sf0,
    const float* __restrict__ w_sf1,
    unsigned short* __restrict__ spike_out, float* __restrict__ filt_out)
{
    __shared__ float wj[2 * AA];
    __shared__ float wcc[AA];
    int tid = threadIdx.x;
    if (tid < 2 * AA) wj[tid] = w_jeff[tid];
    if (tid < AA) wcc[tid] = w_cc[tid];
    __syncthreads();

    int g = blockIdx.x * 256 + tid;     // n*CC + c
    int n = g >> 9;
    int c = g & (CC - 1);

    const float inv_lif = 1.0f / 1.5f;
    float d0 = sig_decay(w_sf0);
    float d1 = sig_decay(w_sf1);

    float s0 = 0.f, s1 = 0.f, v6 = 0.f, u1 = 0.f;
    float v[AA], u[AA];
#pragma unroll
    for (int a = 0; a < AA; a++) { v[a] = 0.f; u[a] = 0.f; }

    const int pL = (n & 31) + 32 * ((c >> 3) & 1);
    const int pks = c >> 4;
    const int pj = c & 7;

    for (int t = 0; t < T_STEPS; t++) {
        const float* xp = x + (size_t)((t * NB + n) * 2) * CC + c;
        s0 = s0 * 0.5f + xp[0];
        s1 = s1 * 0.5f + xp[CC];
        float acc = 0.f;
#pragma unroll
        for (int a = 0; a < AA; a++) {
            float z  = wj[2 * a] * s0 + wj[2 * a + 1] * s1;
            float vv = v[a] + (z - v[a]) * inv_lif;
            bool  sp = vv >= 1.0f;
            v[a] = sp ? 0.0f : vv;
            float uu = u[a] * d0 + (sp ? 1.0f : 0.0f);
            u[a] = uu;
            acc += wcc[a] * uu;
        }
        v6 += acc;
        bool sp6 = v6 >= 1.0f;
        v6 = sp6 ? 0.0f : v6;
        if (spike_out) {
            int mt = (t * NB + n) >> 5;
            size_t adr = (((size_t)mt * 32 + pks) * 64 + pL) * 8 + pj;
            spike_out[adr] = sp6 ? (unsigned short)0x3F80 : (unsigned short)0;
        } else {
            u1 = u1 * d1 + (sp6 ? 1.0f : 0.0f);
            filt_out[(size_t)(t * NB + n) * CC + c] = u1;
        }
    }
}

// ---------------------------------------------------------------------------
// Consumer: sum NPARTS split-K parts of tiled G (fixed order), commuted
// filter, IF, emit spikes.  Double-buffered register tiles of 16 loads with
// sched_barrier fences so the scheduler CANNOT sink loads into the serial
// recurrence (round-9 failure: VGPR=32 showed per-t load sinking).
// ---------------------------------------------------------------------------
template <int NPARTS>
__global__ __launch_bounds__(256) void if_spike_kernel(
    const float* __restrict__ G, size_t partStride,
    const float* __restrict__ w_sf_in, int F, int fshift,
    unsigned short* __restrict__ out_bf, float* __restrict__ out_f32)
{
    constexpr int TT = 16 / NPARTS;           // t's per tile (8 / 4 / 2)
    constexpr int NTILES = T_STEPS / TT;      // 4 / 8 / 16

    int gid = blockIdx.x * 256 + threadIdx.x;   // n*F + f
    int n = gid >> fshift;
    int f = gid & (F - 1);
    const int NT = F >> 5;
    const int NF = NB * F;
    float dz = sig_decay(w_sf_in);

    // G tile offset for step t: ((2t + n>>5)*NT + f>>5)*1024 + (n&31)*32 + (f&31)
    size_t base = ((size_t)(n >> 5) * NT + (f >> 5)) * 1024
                + (size_t)(n & 31) * 32 + (f & 31);
    const size_t tstride = (size_t)2 * NT * 1024;

    float buf[2][NPARTS][TT];
    auto pf = [&](int b, int tile) {
#pragma unroll
        for (int p = 0; p < NPARTS; p++)
#pragma unroll
            for (int j = 0; j < TT; j++)
                buf[b][p][j] = G[(size_t)p * partStride + base
                               + (size_t)(tile * TT + j) * tstride];
    };

    const int pL = (n & 31) + 32 * ((f >> 3) & 1);
    const int KS = F >> 4;

    pf(0, 0);
    float zf = 0.f, v = 0.f;
#pragma unroll
    for (int tile = 0; tile < NTILES; tile++) {
        const int b = tile & 1;
        if (tile + 1 < NTILES) pf(b ^ 1, tile + 1);   // prefetch next tile
        __builtin_amdgcn_sched_barrier(0);            // pin loads above
#pragma unroll
        for (int j = 0; j < TT; j++) {
            int t = tile * TT + j;
            float gsum = buf[b][0][j];
#pragma unroll
            for (int p = 1; p < NPARTS; p++) gsum += buf[b][p][j];
            zf = zf * dz + gsum;      // commuted synapse filter
            v += zf;                  // IF
            bool sp = v >= 1.0f;
            v = sp ? 0.0f : v;
            if (out_bf) {
                int mt = 2 * t + (n >> 5);
                size_t adr = (((size_t)mt * KS + (f >> 4)) * 64 + pL) * 8 + (f & 7);
                out_bf[adr] = sp ? (unsigned short)0x3F80 : (unsigned short)0;
            } else {
                out_f32[(size_t)t * NF + gid] = sp ? 1.0f : 0.0f;
            }
        }
        __builtin_amdgcn_sched_barrier(0);            // pin recurrence above
    }
}

// ---------------------------------------------------------------------------
// Binary-A bf16 MFMA GEMM, packed operands, software-pipelined (round 8).
// ---------------------------------------------------------------------------
__global__ __launch_bounds__(512, 2) void bgemm(
    const unsigned short* __restrict__ Ap,   // packed spikes (M x K)
    const unsigned short* __restrict__ Bp,   // packed 3-plane weights
    float* __restrict__ C,                   // sk partials, tiled
    int N, int K_total, int K_per)
{
    const int NT = N >> 5, KS = K_total >> 4;
    __shared__ uint4 sh[2][1792];            // 2 x 28 KB

    const int tid = threadIdx.x;
    const int wv  = tid >> 6;                // 0..7  (n-tile of this wave)
    const int L   = tid & 63;
    const int bm32 = blockIdx.x * 4;         // m-tile base (128 m)
    const int bn32 = blockIdx.y * 8;         // n-tile base (256 n)
    const int ks0  = (blockIdx.z * K_per) >> 4;
    const int nk   = K_per >> 4;

    f32x16 acc[4];
#pragma unroll
    for (int i = 0; i < 4; i++)
#pragma unroll
        for (int r = 0; r < 16; r++) acc[i][r] = 0.f;

    const uint4* A4 = (const uint4*)Ap;
    const uint4* B4 = (const uint4*)Bp;
    const int ntl = tid >> 6;
    const int cL  = tid & 63;

    uint4 pa, pb0, pb1, pb2;
    auto gload = [&](int ks) {
        if (tid < 256)
            pa = A4[((size_t)(bm32 + (tid >> 6)) * KS + ks) * 64 + (tid & 63)];
        pb0 = B4[((size_t)(0 * NT + bn32 + ntl) * KS + ks) * 64 + cL];
        pb1 = B4[((size_t)(1 * NT + bn32 + ntl) * KS + ks) * 64 + cL];
        pb2 = B4[((size_t)(2 * NT + bn32 + ntl) * KS + ks) * 64 + cL];
    };
    auto lwrite = [&](int b) {
        if (tid < 256) sh[b][tid] = pa;
        sh[b][256 + tid] = pb0;
        sh[b][256 + 512 + tid] = pb1;
        sh[b][256 + 1024 + tid] = pb2;
    };

    bf16x8 af[4], bf[3];
    auto rfrags = [&](int b) {
#pragma unroll
        for (int i = 0; i < 4; i++)
            af[i] = *(const bf16x8*)&sh[b][i * 64 + L];
#pragma unroll
        for (int p = 0; p < 3; p++)
            bf[p] = *(const bf16x8*)&sh[b][256 + (p * 8 + wv) * 64 + L];
    };

    gload(ks0);
    lwrite(0);
    if (nk > 1) gload(ks0 + 1);
    __syncthreads();
    rfrags(0);

    for (int kt = 0; kt < nk; kt++) {
        if (kt + 1 < nk) lwrite((kt + 1) & 1);      // stage k+1 -> other buf
        if (kt + 2 < nk) gload(ks0 + kt + 2);       // stage k+2 -> regs
#pragma unroll
        for (int p = 0; p < 3; p++)
#pragma unroll
            for (int i = 0; i < 4; i++)
                acc[i] = __builtin_amdgcn_mfma_f32_32x32x16_bf16(
                    af[i], bf[p], acc[i], 0, 0, 0);
        if (kt + 1 < nk) {
            __syncthreads();
            rfrags((kt + 1) & 1);
        }
    }

    // C write: 32x32 row-major tiles.  col = lane&31, row = (r&3)+8*(r>>2)+4*(lane>>5)
    float* Cp = C + (size_t)blockIdx.z * ((size_t)MROWS * N);
    const int col = L & 31, rbase = 4 * (L >> 5);
#pragma unroll
    for (int i = 0; i < 4; i++) {
        size_t tb = ((size_t)(bm32 + i) * NT + (bn32 + wv)) * 1024;
#pragma unroll
        for (int r = 0; r < 16; r++) {
            int row = (r & 3) + 8 * (r >> 2) + rbase;
            Cp[tb + row * 32 + col] = acc[i][r];
        }
    }
}

// ---------------------------------------------------------------------------
// Legacy fp32 path (round-3, proven) for small workspace.
// ---------------------------------------------------------------------------
__global__ __launch_bounds__(256) void if_filter_kernel(
    float* __restrict__ buf, size_t partStride, int nparts,
    const float* __restrict__ w_sf, int F)
{
    int tid = blockIdx.x * 256 + threadIdx.x;
    const int NF = NB * F;
    bool  filt = (w_sf != nullptr);
    float d = filt ? sig_decay(w_sf) : 0.0f;
    float v = 0.f, u = 0.f;
    for (int t = 0; t < T_STEPS; t++) {
        size_t off = (size_t)t * NF + tid;
        float zt = buf[off];
        for (int p = 1; p < nparts; p++) zt += buf[p * partStride + off];
        v += zt;
        bool sp = v >= 1.0f;
        v = sp ? 0.0f : v;
        float s = sp ? 1.0f : 0.0f;
        if (filt) { u = u * d + s; buf[off] = u; }
        else      { buf[off] = s; }
    }
}

__global__ __launch_bounds__(256) void gemm_nt(
    const float* __restrict__ A, const float* __restrict__ B,
    float* __restrict__ C, int M, int N, int K_total, int K_per)
{
    constexpr int BM = 64, BN = 64, BK = 32;
    __shared__ float As[BK][BM + 4];
    __shared__ float Bs[BK][BN + 4];
    const int tid = threadIdx.x;
    const int tx  = tid & 15;
    const int ty  = tid >> 4;
    const int bm  = blockIdx.y * BM;
    const int bn  = blockIdx.x * BN;
    const int kbeg = blockIdx.z * K_per;
    float acc[4][4];
#pragma unroll
    for (int i = 0; i < 4; i++)
#pragma unroll
        for (int j = 0; j < 4; j++) acc[i][j] = 0.f;
    const int lrow = tid >> 3;
    const int lkq  = tid & 7;
    for (int kt = 0; kt < K_per; kt += BK) {
        int k0 = kbeg + kt;
        __syncthreads();
#pragma unroll
        for (int i = 0; i < 2; i++) {
            int row = lrow + i * 32;
            float4 av = *(const float4*)(A + (size_t)(bm + row) * K_total + k0 + lkq * 4);
            As[lkq * 4 + 0][row] = av.x;
            As[lkq * 4 + 1][row] = av.y;
            As[lkq * 4 + 2][row] = av.z;
            As[lkq * 4 + 3][row] = av.w;
            float4 bv = *(const float4*)(B + (size_t)(bn + row) * K_total + k0 + lkq * 4);
            Bs[lkq * 4 + 0][row] = bv.x;
            Bs[lkq * 4 + 1][row] = bv.y;
            Bs[lkq * 4 + 2][row] = bv.z;
            Bs[lkq * 4 + 3][row] = bv.w;
        }
        __syncthreads();
#pragma unroll
        for (int kk = 0; kk < BK; kk++) {
            float4 a0 = *(const float4*)&As[kk][ty * 4];
            float4 b0 = *(const float4*)&Bs[kk][tx * 4];
            float ar[4] = {a0.x, a0.y, a0.z, a0.w};
            float br[4] = {b0.x, b0.y, b0.z, b0.w};
#pragma unroll
            for (int i = 0; i < 4; i++)
#pragma unroll
                for (int j = 0; j < 4; j++) acc[i][j] += ar[i] * br[j];
        }
    }
    float* Cp = C + (size_t)blockIdx.z * (size_t)M * N;
#pragma unroll
    for (int i = 0; i < 4; i++) {
        float4 o;
        o.x = acc[i][0]; o.y = acc[i][1]; o.z = acc[i][2]; o.w = acc[i][3];
        *(float4*)(Cp + (size_t)(bm + ty * 4 + i) * N + bn + tx * 4) = o;
    }
}

// ---------------------------------------------------------------------------
// Final: out[t,n] = cumsum_t( dot(s3[t,n,:512], W_out) + b ).  One wave per n.
// ---------------------------------------------------------------------------
__global__ __launch_bounds__(64) void final_kernel(
    const float* __restrict__ y15, const float* __restrict__ W_out,
    const float* __restrict__ b_out, float* __restrict__ out)
{
    int n = blockIdx.x;
    int lane = threadIdx.x;
    float w[8];
#pragma unroll
    for (int j = 0; j < 8; j++) w[j] = W_out[lane + j * 64];
    float b = b_out[0];
    float cum = 0.f;
    for (int t = 0; t < T_STEPS; t++) {
        const float* yp = y15 + (size_t)(t * NB + n) * 512;
        float p = 0.f;
#pragma unroll
        for (int j = 0; j < 8; j++) p += yp[lane + j * 64] * w[j];
#pragma unroll
        for (int off = 32; off > 0; off >>= 1) p += __shfl_down(p, off);
        if (lane == 0) {
            cum += p + b;
            out[t * NB + n] = cum;
        }
    }
}

extern "C" void kernel_launch(void* const* d_in, const int* in_sizes, int n_in,
                              void* d_out, int out_size, void* d_ws, size_t ws_size,
                              hipStream_t stream) {
    (void)in_sizes; (void)n_in; (void)out_size;
    const float* x      = (const float*)d_in[0];
    const float* w_jeff = (const float*)d_in[1];
    const float* w_cc   = (const float*)d_in[2];
    const float* w_sf0  = (const float*)d_in[3];
    const float* W1     = (const float*)d_in[4];
    const float* w_sf1  = (const float*)d_in[5];
    const float* W2     = (const float*)d_in[6];
    const float* w_sf2  = (const float*)d_in[7];
    const float* W3     = (const float*)d_in[8];
    const float* w_sf3  = (const float*)d_in[9];
    const float* W_out  = (const float*)d_in[10];
    const float* b_out  = (const float*)d_in[11];
    float* out = (float*)d_out;
    const int M = MROWS;   // 2048

    const size_t nW1 = (size_t)2048 * 512, nW2 = (size_t)1024 * 2048, nW3 = (size_t)512 * 1024;
    size_t need = 3 * (nW1 + nW2 + nW3) * 2     // packed planes   21 MB
                + (size_t)M * 512 * 2           // s6 packed        2 MB
                + (size_t)2 * M * 2048 * 4      // G shared region 32 MB
                + (size_t)M * 2048 * 2          // s8               8 MB
                + (size_t)M * 1024 * 2          // s10              4 MB
                + (size_t)M * 512 * 4;          // s12              4 MB

    if (ws_size >= need) {
        unsigned short* Bp1 = (unsigned short*)d_ws;
        unsigned short* Bp2 = Bp1 + 3 * nW1;
        unsigned short* Bp3 = Bp2 + 3 * nW2;
        unsigned short* s6  = Bp3 + 3 * nW3;
        float* G   = (float*)(s6 + (size_t)M * 512);          // 2*M*2048 floats
        unsigned short* s8  = (unsigned short*)(G + (size_t)2 * M * 2048);
        unsigned short* s10 = s8 + (size_t)M * 2048;
        float* s12 = (float*)(s10 + (size_t)M * 1024);

        pack_b_kernel<<<(int)(nW1 / 256), 256, 0, stream>>>(W1, Bp1, 2048, 512, 9);
        pack_b_kernel<<<(int)(nW2 / 256), 256, 0, stream>>>(W2, Bp2, 1024, 2048, 11);
        pack_b_kernel<<<(int)(nW3 / 256), 256, 0, stream>>>(W3, Bp3, 512, 1024, 10);

        front_kernel<<<NB * CC / 256, 256, 0, stream>>>(
            x, w_jeff, w_cc, w_sf0, w_sf1, s6, nullptr);

        // GEMM1: N=2048, K=512, sk=2.  grid(m16, n8, sk2) = 256 blocks
        bgemm<<<dim3(16, 8, 2), 512, 0, stream>>>(s6, Bp1, G, 2048, 512, 256);
        if_spike_kernel<2><<<NB * 2048 / 256, 256, 0, stream>>>(
            G, (size_t)M * 2048, w_sf1, 2048, 11, s8, nullptr);

        // GEMM2: N=1024, K=2048, sk=4.  grid(16, 4, 4) = 256 blocks
        bgemm<<<dim3(16, 4, 4), 512, 0, stream>>>(s8, Bp2, G, 1024, 2048, 512);
        if_spike_kernel<4><<<NB * 1024 / 256, 256, 0, stream>>>(
            G, (size_t)M * 1024, w_sf2, 1024, 10, s10, nullptr);

        // GEMM3: N=512, K=1024, sk=8.  grid(16, 2, 8) = 256 blocks
        bgemm<<<dim3(16, 2, 8), 512, 0, stream>>>(s10, Bp3, G, 512, 1024, 128);
        if_spike_kernel<8><<<NB * 512 / 256, 256, 0, stream>>>(
            G, (size_t)M * 512, w_sf3, 512, 9, nullptr, s12);

        final_kernel<<<NB, 64, 0, stream>>>(s12, W_out, b_out, out);
    } else {
        // ---------------- legacy fp32 path (round-3) ----------------
        float* y7  = (float*)d_ws;
        float* z1  = y7 + (size_t)M * 512;
        float* z2p = z1 + (size_t)M * 2048;
        float* z3p = z1;
        size_t need2 = ((size_t)M * 512 + (size_t)M * 2048 + 2 * (size_t)M * 1024) * 4;
        const int ksplit2 = (ws_size >= need2) ? 2 : 1;

        front_kernel<<<NB * CC / 256, 256, 0, stream>>>(
            x, w_jeff, w_cc, w_sf0, w_sf1, nullptr, y7);
        gemm_nt<<<dim3(2048 / 64, 2048 / 64, 1), 256, 0, stream>>>(
            y7, W1, z1, M, 2048, 512, 512);
        if_filter_kernel<<<NB * 2048 / 256, 256, 0, stream>>>(z1, 0, 1, w_sf2, 2048);
        gemm_nt<<<dim3(1024 / 64, 2048 / 64, ksplit2), 256, 0, stream>>>(
            z1, W2, z2p, M, 1024, 2048, 2048 / ksplit2);
        if_filter_kernel<<<NB * 1024 / 256, 256, 0, stream>>>(
            z2p, (size_t)M * 1024, ksplit2, w_sf3, 1024);
        gemm_nt<<<dim3(512 / 64, 2048 / 64, 4), 256, 0, stream>>>(
            z2p, W3, z3p, M, 512, 1024, 1024 / 4);
        if_filter_kernel<<<NB * 512 / 256, 256, 0, stream>>>(
            z3p, (size_t)M * 512, 4, nullptr, 512);
        final_kernel<<<NB, 64, 0, stream>>>(z3p, W_out, b_out, out);
    }
}

// Round 11
// 226.597 us; speedup vs baseline: 1.7816x; 1.0865x over previous
//
#include <hip/hip_runtime.h>
#include <math.h>

#define T_STEPS 32
#define NB 64      // batch
#define CC 512     // channels
#define AA 32      // cc_acc size
#define MROWS (T_STEPS * NB)   // 2048 GEMM rows

typedef __attribute__((ext_vector_type(8)))  short bf16x8;
typedef __attribute__((ext_vector_type(16))) float f32x16;

__device__ __forceinline__ float sig_decay(const float* wp) {
    return 1.0f - 1.0f / (1.0f + expf(-wp[0]));   // 1 - sigmoid(w)
}

__device__ __forceinline__ unsigned short f2bf_rne(float f) {
    unsigned int u = __float_as_uint(f);
    u += 0x7FFF + ((u >> 16) & 1);
    return (unsigned short)(u >> 16);
}

// ===========================================================================
// Packed-operand layouts (verified by rounds 5-10 passing runs):
//   A/B fragment chunk (16 B = 8 bf16): lane L holds row r = (L&31) of a
//   32-row tile, k = 8*(L>>5) + j.  Chunk index:
//     A: (mt*KS + ks)*64 + L          mt = m>>5, ks = k>>4, KS = K/16
//     B: ((p*NT + nt)*KS + ks)*64 + L nt = n>>5, NT = N/32, p = plane
//   C tile (32x32 fp32, row-major): idx = (mt*NT + nt)*1024 + row*32 + col
// ===========================================================================

// ---------------------------------------------------------------------------
// Split ALL three weight matrices into 3 bf16 planes (hi/mid/lo) packed in
// B-fragment order.  One fused launch (was 3).
// ---------------------------------------------------------------------------
#define NW1 (2048 * 512)
#define NW2 (1024 * 2048)
#define NW3 (512 * 1024)

__device__ __forceinline__ void pack_one(
    const float* __restrict__ W, unsigned short* __restrict__ out,
    int idx, int Nw, int Kw, int kshift)
{
    int n = idx >> kshift;
    int k = idx & (Kw - 1);
    float w = W[idx];
    unsigned short h = f2bf_rne(w);
    float fh = __uint_as_float((unsigned int)h << 16);
    float r = w - fh;
    unsigned short m = f2bf_rne(r);
    float fm = __uint_as_float((unsigned int)m << 16);
    unsigned short l = f2bf_rne(r - fm);
    unsigned short vals[3] = {h, m, l};
    const int NT = Nw >> 5, KS = Kw >> 4;
    int L = (n & 31) + 32 * ((k >> 3) & 1);
#pragma unroll
    for (int p = 0; p < 3; p++) {
        size_t chunk = ((size_t)(p * NT + (n >> 5)) * KS + (k >> 4)) * 64 + L;
        out[chunk * 8 + (k & 7)] = vals[p];
    }
}

__global__ __launch_bounds__(256) void pack_all_kernel(
    const float* __restrict__ W1, const float* __restrict__ W2,
    const float* __restrict__ W3,
    unsigned short* __restrict__ B1, unsigned short* __restrict__ B2,
    unsigned short* __restrict__ B3)
{
    int i = blockIdx.x * 256 + threadIdx.x;
    if (i < NW1) {
        pack_one(W1, B1, i, 2048, 512, 9);
    } else if (i < NW1 + NW2) {
        pack_one(W2, B2, i - NW1, 1024, 2048, 11);
    } else if (i < NW1 + NW2 + NW3) {
        pack_one(W3, B3, i - NW1 - NW2, 512, 1024, 10);
    }
}

// ---------------------------------------------------------------------------
// Front end (transpose + synapse tau=2 + jeffress + LIF + sf0 + w_cc + IF).
// spike_out != null: write IF spikes in packed A-fragment order (K = 512).
// ---------------------------------------------------------------------------
__global__ __launch_bounds__(256) void front_kernel(
    const float* __restrict__ x, const float* __restrict__ w_jeff,
    const float* __restrict__ w_cc, const float* __restrict__ w_sf0,
    const float* __restrict__ w_sf1,
    unsigned short* __restrict__ spike_out, float* __restrict__ filt_out)
{
    __shared__ float wj[2 * AA];
    __shared__ float wcc[AA];
    int tid = threadIdx.x;
    if (tid < 2 * AA) wj[tid] = w_jeff[tid];
    if (tid < AA) wcc[tid] = w_cc[tid];
    __syncthreads();

    int g = blockIdx.x * 256 + tid;     // n*CC + c
    int n = g >> 9;
    int c = g & (CC - 1);

    const float inv_lif = 1.0f / 1.5f;
    float d0 = sig_decay(w_sf0);
    float d1 = sig_decay(w_sf1);

    float s0 = 0.f, s1 = 0.f, v6 = 0.f, u1 = 0.f;
    float v[AA], u[AA];
#pragma unroll
    for (int a = 0; a < AA; a++) { v[a] = 0.f; u[a] = 0.f; }

    const int pL = (n & 31) + 32 * ((c >> 3) & 1);
    const int pks = c >> 4;
    const int pj = c & 7;

    for (int t = 0; t < T_STEPS; t++) {
        const float* xp = x + (size_t)((t * NB + n) * 2) * CC + c;
        s0 = s0 * 0.5f + xp[0];
        s1 = s1 * 0.5f + xp[CC];
        float acc = 0.f;
#pragma unroll
        for (int a = 0; a < AA; a++) {
            float z  = wj[2 * a] * s0 + wj[2 * a + 1] * s1;
            float vv = v[a] + (z - v[a]) * inv_lif;
            bool  sp = vv >= 1.0f;
            v[a] = sp ? 0.0f : vv;
            float uu = u[a] * d0 + (sp ? 1.0f : 0.0f);
            u[a] = uu;
            acc += wcc[a] * uu;
        }
        v6 += acc;
        bool sp6 = v6 >= 1.0f;
        v6 = sp6 ? 0.0f : v6;
        if (spike_out) {
            int mt = (t * NB + n) >> 5;
            size_t adr = (((size_t)mt * 32 + pks) * 64 + pL) * 8 + pj;
            spike_out[adr] = sp6 ? (unsigned short)0x3F80 : (unsigned short)0;
        } else {
            u1 = u1 * d1 + (sp6 ? 1.0f : 0.0f);
            filt_out[(size_t)(t * NB + n) * CC + c] = u1;
        }
    }
}

// ---------------------------------------------------------------------------
// Consumer (round-10 proven): sum NPARTS split-K parts, commuted filter,
// IF, emit spikes.  Double-buffered register tiles + sched_barrier fences.
// ---------------------------------------------------------------------------
template <int NPARTS>
__global__ __launch_bounds__(256) void if_spike_kernel(
    const float* __restrict__ G, size_t partStride,
    const float* __restrict__ w_sf_in, int F, int fshift,
    unsigned short* __restrict__ out_bf, float* __restrict__ out_f32)
{
    constexpr int TT = 16 / NPARTS;           // t's per tile (8 / 4 / 2)
    constexpr int NTILES = T_STEPS / TT;      // 4 / 8 / 16

    int gid = blockIdx.x * 256 + threadIdx.x;   // n*F + f
    int n = gid >> fshift;
    int f = gid & (F - 1);
    const int NT = F >> 5;
    const int NF = NB * F;
    float dz = sig_decay(w_sf_in);

    size_t base = ((size_t)(n >> 5) * NT + (f >> 5)) * 1024
                + (size_t)(n & 31) * 32 + (f & 31);
    const size_t tstride = (size_t)2 * NT * 1024;

    float buf[2][NPARTS][TT];
    auto pf = [&](int b, int tile) {
#pragma unroll
        for (int p = 0; p < NPARTS; p++)
#pragma unroll
            for (int j = 0; j < TT; j++)
                buf[b][p][j] = G[(size_t)p * partStride + base
                               + (size_t)(tile * TT + j) * tstride];
    };

    const int pL = (n & 31) + 32 * ((f >> 3) & 1);
    const int KS = F >> 4;

    pf(0, 0);
    float zf = 0.f, v = 0.f;
#pragma unroll
    for (int tile = 0; tile < NTILES; tile++) {
        const int b = tile & 1;
        if (tile + 1 < NTILES) pf(b ^ 1, tile + 1);   // prefetch next tile
        __builtin_amdgcn_sched_barrier(0);            // pin loads above
#pragma unroll
        for (int j = 0; j < TT; j++) {
            int t = tile * TT + j;
            float gsum = buf[b][0][j];
#pragma unroll
            for (int p = 1; p < NPARTS; p++) gsum += buf[b][p][j];
            zf = zf * dz + gsum;      // commuted synapse filter
            v += zf;                  // IF
            bool sp = v >= 1.0f;
            v = sp ? 0.0f : v;
            if (out_bf) {
                int mt = 2 * t + (n >> 5);
                size_t adr = (((size_t)mt * KS + (f >> 4)) * 64 + pL) * 8 + (f & 7);
                out_bf[adr] = sp ? (unsigned short)0x3F80 : (unsigned short)0;
            } else {
                out_f32[(size_t)t * NF + gid] = sp ? 1.0f : 0.0f;
            }
        }
        __builtin_amdgcn_sched_barrier(0);            // pin recurrence above
    }
}

// ---------------------------------------------------------------------------
// Binary-A bf16 MFMA GEMM v2.  128x128 block tile, 256 threads = 4 waves,
// wave = 128m x 32n.  A staged in LDS (shared by all 4 waves, 2 x 4 KB
// double buffer, one barrier/stage).  B (read by only ONE wave each -> LDS
// gained nothing) goes global->register, double-buffered two stages ahead
// with LITERAL buffer indices (macro-expanded stage pair; round-9 lesson:
// runtime-indexed reg buffers get spilled/serialized).  nk must be even.
// Grids are 512 blocks = 2 blocks/CU -> cross-block overlap hides barriers.
// ---------------------------------------------------------------------------
__global__ __launch_bounds__(256, 2) void bgemm(
    const unsigned short* __restrict__ Ap,   // packed spikes (M x K)
    const unsigned short* __restrict__ Bp,   // packed 3-plane weights
    float* __restrict__ C,                   // sk partials, tiled
    int N, int K_total, int K_per)
{
    const int NT = N >> 5, KS = K_total >> 4;
    __shared__ bf16x8 shA[2][256];           // 2 x 4 KB

    const int tid = threadIdx.x;
    const int wv  = tid >> 6;                // 0..3: n-tile of this wave
    const int L   = tid & 63;
    const int bm32 = blockIdx.x * 4;         // 4 m-tiles (128 m)
    const int bn32 = blockIdx.y * 4;         // 4 n-tiles (128 n)
    const int ks0  = (blockIdx.z * K_per) >> 4;
    const int nk   = K_per >> 4;             // even for all our shapes

    f32x16 acc[4];
#pragma unroll
    for (int i = 0; i < 4; i++)
#pragma unroll
        for (int r = 0; r < 16; r++) acc[i][r] = 0.f;

    const bf16x8* A8 = (const bf16x8*)Ap;
    const bf16x8* B8 = (const bf16x8*)Bp;

    bf16x8 pa;                                // A staging reg (1 chunk/thread)
    auto gloadA = [&](int ks) {
        pa = A8[((size_t)(bm32 + wv) * KS + ks) * 64 + L];
    };
    auto lwriteA = [&](int b) { shA[b][tid] = pa; };

    bf16x8 pb0[3], pb1[3];                    // B double buffer (literal idx)
    auto gloadB = [&](int ks, bf16x8* pbuf) {
#pragma unroll
        for (int p = 0; p < 3; p++)
            pbuf[p] = B8[((size_t)(p * NT + bn32 + wv) * KS + ks) * 64 + L];
    };

    bf16x8 af[4];
    auto rfragsA = [&](int b) {
#pragma unroll
        for (int i = 0; i < 4; i++)
            af[i] = shA[b][i * 64 + L];
    };

    // prologue: stage 0 in shA[0]/pb0, stage 1 in pa/pb1
    gloadA(ks0);
    gloadB(ks0, pb0);
    lwriteA(0);
    gloadA(ks0 + 1);
    gloadB(ks0 + 1, pb1);
    __syncthreads();
    rfragsA(0);

#define BG_STAGE(KT, CB, PB)                                                  \
    {                                                                         \
        bf16x8 b0 = PB[0], b1 = PB[1], b2 = PB[2];                            \
        if ((KT) + 1 < nk) lwriteA((CB) ^ 1);          /* pa holds A(KT+1) */ \
        if ((KT) + 2 < nk) {                                                  \
            gloadA(ks0 + (KT) + 2);                                           \
            gloadB(ks0 + (KT) + 2, PB);                                       \
        }                                                                     \
        _Pragma("unroll")                                                     \
        for (int i = 0; i < 4; i++)                                           \
            acc[i] = __builtin_amdgcn_mfma_f32_32x32x16_bf16(af[i], b0, acc[i], 0, 0, 0); \
        _Pragma("unroll")                                                     \
        for (int i = 0; i < 4; i++)                                           \
            acc[i] = __builtin_amdgcn_mfma_f32_32x32x16_bf16(af[i], b1, acc[i], 0, 0, 0); \
        _Pragma("unroll")                                                     \
        for (int i = 0; i < 4; i++)                                           \
            acc[i] = __builtin_amdgcn_mfma_f32_32x32x16_bf16(af[i], b2, acc[i], 0, 0, 0); \
        if ((KT) + 1 < nk) { __syncthreads(); rfragsA((CB) ^ 1); }            \
    }

    for (int kt = 0; kt < nk; kt += 2) {
        BG_STAGE(kt, 0, pb0);
        BG_STAGE(kt + 1, 1, pb1);
    }
#undef BG_STAGE

    // C write: 32x32 row-major tiles.  col = lane&31, row = (r&3)+8*(r>>2)+4*(lane>>5)
    float* Cp = C + (size_t)blockIdx.z * ((size_t)MROWS * N);
    const int col = L & 31, rbase = 4 * (L >> 5);
#pragma unroll
    for (int i = 0; i < 4; i++) {
        size_t tb = ((size_t)(bm32 + i) * NT + (bn32 + wv)) * 1024;
#pragma unroll
        for (int r = 0; r < 16; r++) {
            int row = (r & 3) + 8 * (r >> 2) + rbase;
            Cp[tb + row * 32 + col] = acc[i][r];
        }
    }
}

// ---------------------------------------------------------------------------
// Legacy fp32 path (round-3, proven) for small workspace.
// ---------------------------------------------------------------------------
__global__ __launch_bounds__(256) void if_filter_kernel(
    float* __restrict__ buf, size_t partStride, int nparts,
    const float* __restrict__ w_sf, int F)
{
    int tid = blockIdx.x * 256 + threadIdx.x;
    const int NF = NB * F;
    bool  filt = (w_sf != nullptr);
    float d = filt ? sig_decay(w_sf) : 0.0f;
    float v = 0.f, u = 0.f;
    for (int t = 0; t < T_STEPS; t++) {
        size_t off = (size_t)t * NF + tid;
        float zt = buf[off];
        for (int p = 1; p < nparts; p++) zt += buf[p * partStride + off];
        v += zt;
        bool sp = v >= 1.0f;
        v = sp ? 0.0f : v;
        float s = sp ? 1.0f : 0.0f;
        if (filt) { u = u * d + s; buf[off] = u; }
        else      { buf[off] = s; }
    }
}

__global__ __launch_bounds__(256) void gemm_nt(
    const float* __restrict__ A, const float* __restrict__ B,
    float* __restrict__ C, int M, int N, int K_total, int K_per)
{
    constexpr int BM = 64, BN = 64, BK = 32;
    __shared__ float As[BK][BM + 4];
    __shared__ float Bs[BK][BN + 4];
    const int tid = threadIdx.x;
    const int tx  = tid & 15;
    const int ty  = tid >> 4;
    const int bm  = blockIdx.y * BM;
    const int bn  = blockIdx.x * BN;
    const int kbeg = blockIdx.z * K_per;
    float acc[4][4];
#pragma unroll
    for (int i = 0; i < 4; i++)
#pragma unroll
        for (int j = 0; j < 4; j++) acc[i][j] = 0.f;
    const int lrow = tid >> 3;
    const int lkq  = tid & 7;
    for (int kt = 0; kt < K_per; kt += BK) {
        int k0 = kbeg + kt;
        __syncthreads();
#pragma unroll
        for (int i = 0; i < 2; i++) {
            int row = lrow + i * 32;
            float4 av = *(const float4*)(A + (size_t)(bm + row) * K_total + k0 + lkq * 4);
            As[lkq * 4 + 0][row] = av.x;
            As[lkq * 4 + 1][row] = av.y;
            As[lkq * 4 + 2][row] = av.z;
            As[lkq * 4 + 3][row] = av.w;
            float4 bv = *(const float4*)(B + (size_t)(bn + row) * K_total + k0 + lkq * 4);
            Bs[lkq * 4 + 0][row] = bv.x;
            Bs[lkq * 4 + 1][row] = bv.y;
            Bs[lkq * 4 + 2][row] = bv.z;
            Bs[lkq * 4 + 3][row] = bv.w;
        }
        __syncthreads();
#pragma unroll
        for (int kk = 0; kk < BK; kk++) {
            float4 a0 = *(const float4*)&As[kk][ty * 4];
            float4 b0 = *(const float4*)&Bs[kk][tx * 4];
            float ar[4] = {a0.x, a0.y, a0.z, a0.w};
            float br[4] = {b0.x, b0.y, b0.z, b0.w};
#pragma unroll
            for (int i = 0; i < 4; i++)
#pragma unroll
                for (int j = 0; j < 4; j++) acc[i][j] += ar[i] * br[j];
        }
    }
    float* Cp = C + (size_t)blockIdx.z * (size_t)M * N;
#pragma unroll
    for (int i = 0; i < 4; i++) {
        float4 o;
        o.x = acc[i][0]; o.y = acc[i][1]; o.z = acc[i][2]; o.w = acc[i][3];
        *(float4*)(Cp + (size_t)(bm + ty * 4 + i) * N + bn + tx * 4) = o;
    }
}

// ---------------------------------------------------------------------------
// Final: out[t,n] = cumsum_t( dot(s3[t,n,:512], W_out) + b ).  One wave per n.
// ---------------------------------------------------------------------------
__global__ __launch_bounds__(64) void final_kernel(
    const float* __restrict__ y15, const float* __restrict__ W_out,
    const float* __restrict__ b_out, float* __restrict__ out)
{
    int n = blockIdx.x;
    int lane = threadIdx.x;
    float w[8];
#pragma unroll
    for (int j = 0; j < 8; j++) w[j] = W_out[lane + j * 64];
    float b = b_out[0];
    float cum = 0.f;
    for (int t = 0; t < T_STEPS; t++) {
        const float* yp = y15 + (size_t)(t * NB + n) * 512;
        float p = 0.f;
#pragma unroll
        for (int j = 0; j < 8; j++) p += yp[lane + j * 64] * w[j];
#pragma unroll
        for (int off = 32; off > 0; off >>= 1) p += __shfl_down(p, off);
        if (lane == 0) {
            cum += p + b;
            out[t * NB + n] = cum;
        }
    }
}

extern "C" void kernel_launch(void* const* d_in, const int* in_sizes, int n_in,
                              void* d_out, int out_size, void* d_ws, size_t ws_size,
                              hipStream_t stream) {
    (void)in_sizes; (void)n_in; (void)out_size;
    const float* x      = (const float*)d_in[0];
    const float* w_jeff = (const float*)d_in[1];
    const float* w_cc   = (const float*)d_in[2];
    const float* w_sf0  = (const float*)d_in[3];
    const float* W1     = (const float*)d_in[4];
    const float* w_sf1  = (const float*)d_in[5];
    const float* W2     = (const float*)d_in[6];
    const float* w_sf2  = (const float*)d_in[7];
    const float* W3     = (const float*)d_in[8];
    const float* w_sf3  = (const float*)d_in[9];
    const float* W_out  = (const float*)d_in[10];
    const float* b_out  = (const float*)d_in[11];
    float* out = (float*)d_out;
    const int M = MROWS;   // 2048

    const size_t nW1 = NW1, nW2 = NW2, nW3 = NW3;
    size_t need = 3 * (nW1 + nW2 + nW3) * 2     // packed planes   21 MB
                + (size_t)M * 512 * 2           // s6 packed        2 MB
                + (size_t)2 * M * 2048 * 4      // G shared region 32 MB
                + (size_t)M * 2048 * 2          // s8               8 MB
                + (size_t)M * 1024 * 2          // s10              4 MB
                + (size_t)M * 512 * 4;          // s12              4 MB

    if (ws_size >= need) {
        unsigned short* Bp1 = (unsigned short*)d_ws;
        unsigned short* Bp2 = Bp1 + 3 * nW1;
        unsigned short* Bp3 = Bp2 + 3 * nW2;
        unsigned short* s6  = Bp3 + 3 * nW3;
        float* G   = (float*)(s6 + (size_t)M * 512);          // 2*M*2048 floats
        unsigned short* s8  = (unsigned short*)(G + (size_t)2 * M * 2048);
        unsigned short* s10 = s8 + (size_t)M * 2048;
        float* s12 = (float*)(s10 + (size_t)M * 1024);

        pack_all_kernel<<<(int)((nW1 + nW2 + nW3 + 255) / 256), 256, 0, stream>>>(
            W1, W2, W3, Bp1, Bp2, Bp3);

        front_kernel<<<NB * CC / 256, 256, 0, stream>>>(
            x, w_jeff, w_cc, w_sf0, w_sf1, s6, nullptr);

        // GEMM1: N=2048, K=512, sk=2.  grid(16m, 16n, 2) = 512 blocks
        bgemm<<<dim3(16, 16, 2), 256, 0, stream>>>(s6, Bp1, G, 2048, 512, 256);
        if_spike_kernel<2><<<NB * 2048 / 256, 256, 0, stream>>>(
            G, (size_t)M * 2048, w_sf1, 2048, 11, s8, nullptr);

        // GEMM2: N=1024, K=2048, sk=4.  grid(16, 8, 4) = 512 blocks
        bgemm<<<dim3(16, 8, 4), 256, 0, stream>>>(s8, Bp2, G, 1024, 2048, 512);
        if_spike_kernel<4><<<NB * 1024 / 256, 256, 0, stream>>>(
            G, (size_t)M * 1024, w_sf2, 1024, 10, s10, nullptr);

        // GEMM3: N=512, K=1024, sk=8.  grid(16, 4, 8) = 512 blocks
        bgemm<<<dim3(16, 4, 8), 256, 0, stream>>>(s10, Bp3, G, 512, 1024, 128);
        if_spike_kernel<8><<<NB * 512 / 256, 256, 0, stream>>>(
            G, (size_t)M * 512, w_sf3, 512, 9, nullptr, s12);

        final_kernel<<<NB, 64, 0, stream>>>(s12, W_out, b_out, out);
    } else {
        // ---------------- legacy fp32 path (round-3) ----------------
        float* y7  = (float*)d_ws;
        float* z1  = y7 + (size_t)M * 512;
        float* z2p = z1 + (size_t)M * 2048;
        float* z3p = z1;
        size_t need2 = ((size_t)M * 512 + (size_t)M * 2048 + 2 * (size_t)M * 1024) * 4;
        const int ksplit2 = (ws_size >= need2) ? 2 : 1;

        front_kernel<<<NB * CC / 256, 256, 0, stream>>>(
            x, w_jeff, w_cc, w_sf0, w_sf1, nullptr, y7);
        gemm_nt<<<dim3(2048 / 64, 2048 / 64, 1), 256, 0, stream>>>(
            y7, W1, z1, M, 2048, 512, 512);
        if_filter_kernel<<<NB * 2048 / 256, 256, 0, stream>>>(z1, 0, 1, w_sf2, 2048);
        gemm_nt<<<dim3(1024 / 64, 2048 / 64, ksplit2), 256, 0, stream>>>(
            z1, W2, z2p, M, 1024, 2048, 2048 / ksplit2);
        if_filter_kernel<<<NB * 1024 / 256, 256, 0, stream>>>(
            z2p, (size_t)M * 1024, ksplit2, w_sf3, 1024);
        gemm_nt<<<dim3(512 / 64, 2048 / 64, 4), 256, 0, stream>>>(
            z2p, W3, z3p, M, 512, 1024, 1024 / 4);
        if_filter_kernel<<<NB * 512 / 256, 256, 0, stream>>>(
            z3p, (size_t)M * 512, 4, nullptr, 512);
        final_kernel<<<NB, 64, 0, stream>>>(z3p, W_out, b_out, out);
    }
}